// Round 12
// baseline (139.739 us; speedup 1.0000x reference)
//
#include <hip/hip_runtime.h>
#include <hip/hip_bf16.h>
#include <stdint.h>

typedef __bf16 bf16;
typedef __attribute__((ext_vector_type(8))) __bf16 bf16x8;
typedef __attribute__((ext_vector_type(4))) __bf16 bf16x4;
typedef __attribute__((ext_vector_type(4))) float f32x4;
typedef __attribute__((ext_vector_type(16))) float f32x16;

#define MFMA16(a, b, c) __builtin_amdgcn_mfma_f32_16x16x32_bf16((a), (b), (c), 0, 0, 0)
#define MFMA32(a, b, c) __builtin_amdgcn_mfma_f32_32x32x16_bf16((a), (b), (c), 0, 0, 0)

// log2(e) / sqrt(1024)
#define QSCALE 0.045084220027780106f

__device__ __forceinline__ void glds16(const void* g, void* l) {
  __builtin_amdgcn_global_load_lds(
      (const __attribute__((address_space(1))) void*)g,
      (__attribute__((address_space(3))) void*)l, 16, 0, 0);
}

// swizzled 16B fragment read from a [rows][64] bf16 tile (128B rows, XOR-16 swizzle)
__device__ __forceinline__ bf16x8 ldsfrag(const unsigned char* base, int row, int colb) {
  return *(const bf16x8*)(base + row * 128 + (colb ^ ((row & 7) << 4)));
}

__device__ __forceinline__ uint32_t pkbf16(float a, float b) {
  uint32_t r;
  asm("v_cvt_pk_bf16_f32 %0, %1, %2" : "=v"(r) : "v"(a), "v"(b));
  return r;
}

// raw v_exp_f32: args here are far from the subnormal range, skip libm's fixup
__device__ __forceinline__ float fexp2(float x) {
#if __has_builtin(__builtin_amdgcn_exp2f)
  return __builtin_amdgcn_exp2f(x);
#else
  float r;
  asm("v_exp_f32 %0, %1" : "=v"(r) : "v"(x));
  return r;
#endif
}

__device__ __forceinline__ f32x16 zero16() {
  f32x16 v;
#pragma unroll
  for (int i = 0; i < 16; ++i) v[i] = 0.f;
  return v;
}

// ---------------- prep kernels ----------------
__global__ __launch_bounds__(256) void k_prep_x(const float* __restrict__ x, bf16* __restrict__ xb) {
  int gid = blockIdx.x * 256 + threadIdx.x;
  const f32x4* xv = (const f32x4*)x;
  f32x4 a = xv[(size_t)gid * 2], b = xv[(size_t)gid * 2 + 1];
  bf16x8 o;
#pragma unroll
  for (int i = 0; i < 4; ++i) { o[i] = (bf16)a[i]; o[i + 4] = (bf16)b[i]; }
  *(bf16x8*)(xb + (size_t)gid * 8) = o;
}

// LDS-tiled transpose: W[1024][C] f32 -> WT[C'][1024] bf16 (coalesced reads, full-line writes).
// MODE 0: C=3072, j = permuted qkv column, Q-columns (which==0) pre-scaled by QSCALE.
// MODE 1: C=1024, j = c.
template <int MODE>
__global__ __launch_bounds__(256) void k_prep_w(const float* __restrict__ W, bf16* __restrict__ WT) {
  __shared__ float tile[64][256];
  const int C = (MODE == 0) ? 3072 : 1024;
  const int c0 = blockIdx.x * 256, k0 = blockIdx.y * 64;
  const int lw = threadIdx.x & 63, w = threadIdx.x >> 6;
#pragma unroll
  for (int i = 0; i < 16; ++i) {
    int r = i * 4 + w;
    f32x4 v = *(const f32x4*)(W + (size_t)(k0 + r) * C + c0 + lw * 4);
    *(f32x4*)&tile[r][lw * 4] = v;
  }
  __syncthreads();
  const int c = c0 + threadIdx.x;
  int j;
  float sc = 1.0f;
  if (MODE == 0) {
    int h = c / 192, rem = c - h * 192, dd = rem / 3, wh = rem - dd * 3;
    j = wh * 1024 + h * 64 + dd;
    if (wh == 0) sc = QSCALE;
  } else {
    j = c;
  }
#pragma unroll
  for (int ch = 0; ch < 8; ++ch) {
    bf16x8 o;
#pragma unroll
    for (int i = 0; i < 8; ++i) o[i] = (bf16)(tile[ch * 8 + i][threadIdx.x] * sc);
    *(bf16x8*)(WT + (size_t)j * 1024 + k0 + ch * 8) = o;
  }
}

__global__ __launch_bounds__(256) void k_prep_bias(const float* __restrict__ bqkv, float* __restrict__ bp) {
  int gid = blockIdx.x * 256 + threadIdx.x;  // gid = j in [0,3072)
  int wj = gid >> 10, rr = gid & 1023, hh = rr >> 6, d2 = rr & 63;
  float v = bqkv[hh * 192 + d2 * 3 + wj];
  bp[gid] = (wj == 0) ? v * QSCALE : v;
}

// ---------------- 128x128 GEMM, K=1024: C = A[M][1024] @ BT[N][1024]^T + bias ----------------
// EPI 0: Q/K -> [b,h,n,64] bf16 (qk base, K at +4194304); V -> VT [b,h,64,n] bf16 (fused transpose)
// EPI 1: fp32 out[M][1024] + bias
template <int EPI>
__global__ __launch_bounds__(256) void k_gemm(const bf16* __restrict__ A, const bf16* __restrict__ BT,
                                              const float* __restrict__ bias, bf16* __restrict__ qk,
                                              bf16* __restrict__ vt, float* __restrict__ outf) {
  __shared__ __align__(16) unsigned char sA[16384];
  __shared__ __align__(16) unsigned char sB[16384];
  const int tid = threadIdx.x;
  const int l = tid & 63, w = tid >> 6, g = l >> 4, l15 = l & 15;
  const int wr = w >> 1, wc = w & 1;
  const int bm = blockIdx.y, bn = blockIdx.x;
  const unsigned char* Ab = (const unsigned char*)A + (size_t)bm * 128 * 2048;
  const unsigned char* Bb = (const unsigned char*)BT + (size_t)bn * 128 * 2048;
  f32x4 acc[4][4];
#pragma unroll
  for (int mi = 0; mi < 4; ++mi)
#pragma unroll
    for (int ni = 0; ni < 4; ++ni) acc[mi][ni] = (f32x4){0.f, 0.f, 0.f, 0.f};

  for (int kt = 0; kt < 16; ++kt) {
    const int k0b = kt * 128;  // 64 bf16 = 128 bytes per K-tile
#pragma unroll
    for (int p = 0; p < 4; ++p) {
      int co = (p * 256 + tid) * 16;
      int row = co >> 7, wb = co & 127;
      int sw = wb ^ ((row & 7) << 4);  // pre-swizzled global source, linear LDS dest
      glds16(Ab + (size_t)row * 2048 + k0b + sw, sA + co);
      glds16(Bb + (size_t)row * 2048 + k0b + sw, sB + co);
    }
    __syncthreads();
#pragma unroll
    for (int ks = 0; ks < 2; ++ks) {
      bf16x8 af[4], bfr[4];
#pragma unroll
      for (int mi = 0; mi < 4; ++mi) af[mi] = ldsfrag(sA, wr * 64 + mi * 16 + l15, ks * 64 + g * 16);
#pragma unroll
      for (int ni = 0; ni < 4; ++ni) bfr[ni] = ldsfrag(sB, wc * 64 + ni * 16 + l15, ks * 64 + g * 16);
      __builtin_amdgcn_s_setprio(1);
#pragma unroll
      for (int mi = 0; mi < 4; ++mi)
#pragma unroll
        for (int ni = 0; ni < 4; ++ni) acc[mi][ni] = MFMA16(af[mi], bfr[ni], acc[mi][ni]);
      __builtin_amdgcn_s_setprio(0);
    }
    __syncthreads();
  }
#pragma unroll
  for (int ni = 0; ni < 4; ++ni) {
    int j = bn * 128 + wc * 64 + ni * 16 + l15;
    float bj = bias[j];
#pragma unroll
    for (int mi = 0; mi < 4; ++mi) {
      int m0 = bm * 128 + wr * 64 + mi * 16 + g * 4;  // C/D: row=(l>>4)*4+reg, col=l&15
      float v[4];
#pragma unroll
      for (int rr = 0; rr < 4; ++rr) v[rr] = acc[mi][ni][rr] + bj;
      if (EPI == 0) {
        int which = j >> 10, r = j & 1023, h = r >> 6, dd = r & 63;
        int b = m0 >> 11, nn = m0 & 2047;
        if (which < 2) {
#pragma unroll
          for (int rr = 0; rr < 4; ++rr)
            qk[(size_t)which * 4194304 + (((size_t)b * 16 + h) * 2048 + nn + rr) * 64 + dd] = (bf16)v[rr];
        } else {
          bf16x4 pw = {(bf16)v[0], (bf16)v[1], (bf16)v[2], (bf16)v[3]};
          *(bf16x4*)(vt + (((size_t)b * 16 + h) * 64 + dd) * 2048 + nn) = pw;
        }
      } else {
#pragma unroll
        for (int rr = 0; rr < 4; ++rr) outf[(size_t)(m0 + rr) * 1024 + j] = v[rr];
      }
    }
  }
}

// ---------------- flash attention: r12 = r9 body + T4 counted-vmcnt skeleton ----------------
// r11 post-mortem: interleave spilled (VGPR 128 wall, 15MB scratch) -> reverted to r9 body.
// r12 change (sync skeleton only): K,V triple-buffered; stage K(t+3),V(t+2) at iter t; end each
// iter with s_waitcnt vmcnt(4) + raw s_barrier instead of __syncthreads. The wait covers only
// LAST iter's stages; this iter's 4 loads stay in flight across the barrier (T4: never drain
// to 0 in the loop). sched_barrier(0) fences per rule #18. Buffer indices and pb ping-pong are
// compile-time via a period-6 unrolled loop. FP stream identical to r9 -> absmax must stay
// exactly 9.766e-4 (race canary for this sync edit). LDS 100352 B -> 1 block/CU (= r9 occupancy).
__global__ __launch_bounds__(512, 1) void k_attn(const bf16* __restrict__ Qg, const bf16* __restrict__ Kg,
                                                 const bf16* __restrict__ VTg, bf16* __restrict__ Og) {
  // [0,49152): K tiles [grp][3 bufs][8192]      (epilogue: mbuf, 64KB spans K+V regions)
  // [49152,98304): V tiles [grp][3 bufs][8192]  (epilogue: sO per g0-wave at +65536)
  // [98304,100352): lsum merge buf [4 waves][2 qt][64] f32
  __shared__ __align__(16) unsigned char smem[100352];
  const int tid = threadIdx.x;
  const int l = tid & 63, w = tid >> 6;
  const int q = l & 31, hi = l >> 5;
  const int g = w >> 2, wl = w & 3;
  const int stid = tid & 255;

  const int bid = blockIdx.x;                  // 256 blocks
  const int wg = (bid & 7) * 32 + (bid >> 3);  // XCD-chunked: 4 consecutive bh per XCD
  const int bh = wg >> 3;
  const int q0w = (wg & 7) * 256 + wl * 64;    // this wave's 64 q-rows

  // Q B-fragments (Q pre-scaled by log2e/32): qf[qt][ks] = Q[q0w+qt*32+q][ks*16 + hi*8 + j]
  bf16x8 qf[2][4];
#pragma unroll
  for (int qt = 0; qt < 2; ++qt)
#pragma unroll
    for (int ks = 0; ks < 4; ++ks)
      qf[qt][ks] = *(const bf16x8*)(Qg + ((size_t)bh * 2048 + q0w + qt * 32 + q) * 64 + ks * 16 + hi * 8);

  f32x16 oacc[2][2];  // [qt][dt] O^T[dd][q]: col q = l&31, row dd = dt*32 + (reg&3)+8*(reg>>2)+4*hi
#pragma unroll
  for (int qt = 0; qt < 2; ++qt) { oacc[qt][0] = zero16(); oacc[qt][1] = zero16(); }
  float lrun4[2][4] = {{0.f, 0.f, 0.f, 0.f}, {0.f, 0.f, 0.f, 0.f}};
  bf16x8 pbA[2][4], pbB[2][4];  // packed P ping-pong (named: compile-time indexing)

  const unsigned char* Kb = (const unsigned char*)Kg + (size_t)bh * 262144 + (size_t)g * 131072;
  const unsigned char* Vb = (const unsigned char*)VTg + (size_t)bh * 262144 + (size_t)g * 2048;
  unsigned char* sKg = smem + g * 24576;
  unsigned char* sVg = smem + 49152 + g * 24576;

  // per-thread staging coords (loop-invariant)
  const int co0 = stid * 16, co1 = (256 + stid) * 16;
  const int row0 = co0 >> 7, row1 = co1 >> 7;
  const int sw0 = (co0 & 127) ^ ((row0 & 7) << 4), sw1 = (co1 & 127) ^ ((row1 & 7) << 4);

#define STAGE_K(kb_, buf_)                                                        \
  do {                                                                            \
    const unsigned char* Ksrc = Kb + (size_t)(kb_) * 8192;                        \
    glds16(Ksrc + (co0 & ~127) + sw0, sKg + (buf_) * 8192 + co0);                 \
    glds16(Ksrc + (co1 & ~127) + sw1, sKg + (buf_) * 8192 + co1);                 \
  } while (0)
#define STAGE_V(kb_, buf_)                                                        \
  do {                                                                            \
    glds16(Vb + (size_t)row0 * 4096 + (size_t)(kb_) * 128 + sw0, sVg + (buf_) * 8192 + co0); \
    glds16(Vb + (size_t)row1 * 4096 + (size_t)(kb_) * 128 + sw1, sVg + (buf_) * 8192 + co1); \
  } while (0)

// counted vmem wait + raw barrier (T4): this iter's stages stay in flight
#define VMWAIT(n)                                                                 \
  do {                                                                            \
    asm volatile("s_waitcnt vmcnt(" #n ")" ::: "memory");                         \
    __builtin_amdgcn_sched_barrier(0);                                            \
  } while (0)
#define RAWBAR()                                                                  \
  do {                                                                            \
    __builtin_amdgcn_sched_barrier(0);                                            \
    __builtin_amdgcn_s_barrier();                                                 \
    __builtin_amdgcn_sched_barrier(0);                                            \
  } while (0)

  // QK^T + exp + pack for one 64-key tile, both qt subtiles sharing the K fragments (r9 body)
#define QK_EXP_PACK(kbase_, PBOUT)                                                \
  do {                                                                            \
    _Pragma("unroll") for (int kt = 0; kt < 2; ++kt) {                            \
      bf16x8 kf[4];                                                               \
      _Pragma("unroll") for (int ks = 0; ks < 4; ++ks)                            \
        kf[ks] = ldsfrag((kbase_), kt * 32 + q, ks * 32 + hi * 16);               \
      _Pragma("unroll") for (int qt = 0; qt < 2; ++qt) {                          \
        f32x16 sacc = zero16();                                                   \
        __builtin_amdgcn_s_setprio(1);                                            \
        _Pragma("unroll") for (int ks = 0; ks < 4; ++ks)                          \
          sacc = MFMA32(kf[ks], qf[qt][ks], sacc);                                \
        __builtin_amdgcn_s_setprio(0);                                            \
        float pe[16];                                                             \
        _Pragma("unroll") for (int r = 0; r < 16; ++r) pe[r] = fexp2(sacc[r]);    \
        _Pragma("unroll") for (int m = 0; m < 4; ++m)                             \
          _Pragma("unroll") for (int j = 0; j < 4; ++j) lrun4[qt][j] += pe[4 * m + j]; \
        uint32_t c[4][2];                                                         \
        _Pragma("unroll") for (int m = 0; m < 4; ++m) {                           \
          c[m][0] = pkbf16(pe[4 * m], pe[4 * m + 1]);                             \
          c[m][1] = pkbf16(pe[4 * m + 2], pe[4 * m + 3]);                         \
        }                                                                         \
        _Pragma("unroll") for (int s = 0; s < 2; ++s) {                           \
          uint32_t x0 = c[2 * s][0], y0 = c[2 * s + 1][0];                        \
          uint32_t x1 = c[2 * s][1], y1 = c[2 * s + 1][1];                        \
          asm("v_permlane32_swap_b32 %0, %1" : "+v"(x0), "+v"(y0));               \
          asm("v_permlane32_swap_b32 %0, %1" : "+v"(x1), "+v"(y1));               \
          union { uint32_t u[4]; bf16x8 v; } bfr;                                 \
          bfr.u[0] = x0; bfr.u[1] = x1; bfr.u[2] = y0; bfr.u[3] = y1;             \
          PBOUT[qt][kt * 2 + s] = bfr.v;                                          \
        }                                                                         \
      }                                                                           \
    }                                                                             \
  } while (0)

  // PV: both qt share each V fragment (ks order 0..3 per [qt][dt] -> r9 FP order)
#define PV_TILE(vbase_, PB)                                                       \
  do {                                                                            \
    __builtin_amdgcn_s_setprio(1);                                                \
    _Pragma("unroll") for (int ks = 0; ks < 4; ++ks)                              \
      _Pragma("unroll") for (int dt = 0; dt < 2; ++dt) {                          \
        bf16x8 vf = ldsfrag((vbase_), dt * 32 + q, ks * 32 + hi * 16);            \
        _Pragma("unroll") for (int qtp = 0; qtp < 2; ++qtp)                       \
          oacc[qtp][dt] = MFMA32(vf, PB[qtp][ks], oacc[qtp][dt]);                 \
      }                                                                           \
    __builtin_amdgcn_s_setprio(0);                                                \
  } while (0)

  // steady iter t: reads K(t+1) from buf (t+1)%3, V(t) from buf t%3;
  // stages K(t+3) -> buf t%3, V(t+2) -> buf (t+2)%3. Counted wait keeps this iter's 4 in flight.
#define ITER(T, KR, VR, KS, VS, DOKS, DOVS, PBIN, PBOUT, VM)                      \
  do {                                                                            \
    if (DOKS) STAGE_K((T) + 3, KS);                                               \
    if (DOVS) STAGE_V((T) + 2, VS);                                               \
    PV_TILE(sVg + (VR) * 8192, PBIN);                                             \
    QK_EXP_PACK(sKg + (KR) * 8192, PBOUT);                                        \
    VMWAIT(VM);                                                                   \
    RAWBAR();                                                                     \
  } while (0)

  // ---- prologue: stage K0,V0,K1,V1,K2 (10 loads); P(0) -> pbA ----
  STAGE_K(0, 0);
  STAGE_V(0, 0);
  STAGE_K(1, 1);
  STAGE_V(1, 1);
  STAGE_K(2, 2);
  VMWAIT(6);   // K0,V0 landed (K1,V1,K2 in flight); Q-loads drained too
  RAWBAR();
  QK_EXP_PACK(sKg, pbA);  // tile 0 from K buf 0
  VMWAIT(2);   // K1,V1 landed (K2 in flight)
  RAWBAR();

  // ---- steady state t=0..14 (period-6 unroll keeps bufs+pb compile-time) ----
  for (int t0 = 0; t0 < 12; t0 += 6) {
    ITER(t0 + 0, 1, 0, 0, 2, 1, 1, pbA, pbB, 4);
    ITER(t0 + 1, 2, 1, 1, 0, 1, 1, pbB, pbA, 4);
    ITER(t0 + 2, 0, 2, 2, 1, 1, 1, pbA, pbB, 4);
    ITER(t0 + 3, 1, 0, 0, 2, 1, 1, pbB, pbA, 4);
    ITER(t0 + 4, 2, 1, 1, 0, 1, 1, pbA, pbB, 4);
    ITER(t0 + 5, 0, 2, 2, 1, 1, 1, pbB, pbA, 4);
  }
  ITER(12, 1, 0, 0, 2, 1, 1, pbA, pbB, 4);  // stages K(15), V(14)
  ITER(13, 2, 1, 1, 0, 0, 1, pbB, pbA, 2);  // stages V(15) only
  ITER(14, 0, 2, 2, 1, 0, 0, pbA, pbB, 0);  // no stages; drain all
  PV_TILE(sVg + 0 * 8192, pbB);             // tile 15 (V15 in buf 0)

#undef STAGE_K
#undef STAGE_V
#undef VMWAIT
#undef RAWBAR
#undef QK_EXP_PACK
#undef PV_TILE
#undef ITER

  __syncthreads();  // full drain before LDS reuse (epilogue)

  float lrun[2];
#pragma unroll
  for (int qt = 0; qt < 2; ++qt)
    lrun[qt] = (lrun4[qt][0] + lrun4[qt][1]) + (lrun4[qt][2] + lrun4[qt][3]);

  // ---- merge the two KV halves (additive: no-max softmax), then transpose O^T and store ----
  float* mbuf = (float*)smem;           // [4 waves][2 qt][32 regs][64 lanes] f32 = 64KB
  float* lb = (float*)(smem + 98304);   // [4 waves][2 qt][64]
  if (g == 1) {
#pragma unroll
    for (int qt = 0; qt < 2; ++qt) {
#pragma unroll
      for (int dt = 0; dt < 2; ++dt)
#pragma unroll
        for (int r = 0; r < 16; ++r)
          mbuf[((wl * 64 + qt * 32 + dt * 16 + r) << 6) + l] = oacc[qt][dt][r];
      lb[(wl * 2 + qt) * 64 + l] = lrun[qt];
    }
  }
  __syncthreads();
  if (g == 0) {
#pragma unroll
    for (int qt = 0; qt < 2; ++qt)
#pragma unroll
      for (int dt = 0; dt < 2; ++dt)
#pragma unroll
        for (int r = 0; r < 16; ++r)
          oacc[qt][dt][r] += mbuf[((wl * 64 + qt * 32 + dt * 16 + r) << 6) + l];
  }
  __syncthreads();  // mbuf reads done before sO region reuse below
  if (g == 0) {
    const int b = bh >> 4, h = bh & 15;
    unsigned char* sO = smem + 65536 + wl * 4096;  // per-wave [32 q][64 dd] bf16, XOR-16 swizzled
#pragma unroll
    for (int qt = 0; qt < 2; ++qt) {
      float lr = lrun[qt] + lb[(wl * 2 + qt) * 64 + l];
      float ps = lr + __shfl_xor(lr, 32);
      float linv = 1.0f / ps;
#pragma unroll
      for (int dt = 0; dt < 2; ++dt)
#pragma unroll
        for (int m = 0; m < 4; ++m) {
          uint32_t b0 = pkbf16(oacc[qt][dt][4 * m] * linv, oacc[qt][dt][4 * m + 1] * linv);
          uint32_t b1 = pkbf16(oacc[qt][dt][4 * m + 2] * linv, oacc[qt][dt][4 * m + 3] * linv);
          int byteo = (dt * 64 + m * 16 + hi * 8) ^ ((q & 7) << 4);
          uint32_t* dst = (uint32_t*)(sO + q * 128 + byteo);
          dst[0] = b0; dst[1] = b1;
        }
      const int q0 = q0w + qt * 32;
#pragma unroll
      for (int rd = 0; rd < 4; ++rd) {
        int byteo = hi * 64 + rd * 16;
        bf16x8 v = *(const bf16x8*)(sO + q * 128 + (byteo ^ ((q & 7) << 4)));
        *(bf16x8*)(Og + ((size_t)b * 2048 + q0 + q) * 1024 + h * 64 + byteo / 2) = v;
      }
    }
  }
}

extern "C" void kernel_launch(void* const* d_in, const int* in_sizes, int n_in,
                              void* d_out, int out_size, void* d_ws, size_t ws_size,
                              hipStream_t stream) {
  const float* x = (const float*)d_in[0];
  const float* Wqkv = (const float*)d_in[1];
  const float* bqkv = (const float*)d_in[2];
  const float* Wproj = (const float*)d_in[3];
  const float* bproj = (const float*)d_in[4];
  float* out = (float*)d_out;
  char* ws = (char*)d_ws;

  bf16* XB = (bf16*)(ws + 0);            // 8 MB x_bf16 [4096][1024]; reused as attn-out
  bf16* WQT = (bf16*)(ws + 8388608);     // 6 MB WqkvT (permuted, Q pre-scaled) [3072][1024]
  float* BQP = (float*)(ws + 14680064);  // 16 KB permuted bias (Q part pre-scaled)
  bf16* WPT = (bf16*)(ws + 14696448);    // 2 MB WprojT [1024][1024]
  bf16* Q = (bf16*)(ws + 16793600);      // 8 MB [2][16][2048][64]
  bf16* K = (bf16*)(ws + 25182208);      // 8 MB (contiguous after Q: qk base + 4194304 elems)
  bf16* VT = (bf16*)(ws + 33570816);     // 8 MB [2][16][64][2048] (written directly by gemm<0>)
  bf16* AO = XB;
  (void)K;
  (void)ws_size;

  k_prep_x<<<2048, 256, 0, stream>>>(x, XB);
  k_prep_w<0><<<dim3(12, 16), 256, 0, stream>>>(Wqkv, WQT);
  k_prep_w<1><<<dim3(4, 16), 256, 0, stream>>>(Wproj, WPT);
  k_prep_bias<<<12, 256, 0, stream>>>(bqkv, BQP);
  k_gemm<0><<<dim3(24, 32), 256, 0, stream>>>(XB, WQT, BQP, Q, VT, nullptr);
  k_attn<<<256, 512, 0, stream>>>(Q, Q + 4194304, VT, AO);
  k_gemm<1><<<dim3(8, 32), 256, 0, stream>>>(AO, WPT, bproj, nullptr, nullptr, out);
}

// Round 13
// 139.524 us; speedup vs baseline: 1.0015x; 1.0015x over previous
//
#include <hip/hip_runtime.h>
#include <hip/hip_bf16.h>
#include <stdint.h>

typedef __bf16 bf16;
typedef __attribute__((ext_vector_type(8))) __bf16 bf16x8;
typedef __attribute__((ext_vector_type(4))) __bf16 bf16x4;
typedef __attribute__((ext_vector_type(4))) float f32x4;
typedef __attribute__((ext_vector_type(16))) float f32x16;

#define MFMA16(a, b, c) __builtin_amdgcn_mfma_f32_16x16x32_bf16((a), (b), (c), 0, 0, 0)
#define MFMA32(a, b, c) __builtin_amdgcn_mfma_f32_32x32x16_bf16((a), (b), (c), 0, 0, 0)

// log2(e) / sqrt(1024)
#define QSCALE 0.045084220027780106f

__device__ __forceinline__ void glds16(const void* g, void* l) {
  __builtin_amdgcn_global_load_lds(
      (const __attribute__((address_space(1))) void*)g,
      (__attribute__((address_space(3))) void*)l, 16, 0, 0);
}

// swizzled 16B fragment read from a [rows][64] bf16 tile (128B rows, XOR-16 swizzle)
__device__ __forceinline__ bf16x8 ldsfrag(const unsigned char* base, int row, int colb) {
  return *(const bf16x8*)(base + row * 128 + (colb ^ ((row & 7) << 4)));
}

__device__ __forceinline__ uint32_t pkbf16(float a, float b) {
  uint32_t r;
  asm("v_cvt_pk_bf16_f32 %0, %1, %2" : "=v"(r) : "v"(a), "v"(b));
  return r;
}

// raw v_exp_f32: args here are far from the subnormal range, skip libm's fixup
__device__ __forceinline__ float fexp2(float x) {
#if __has_builtin(__builtin_amdgcn_exp2f)
  return __builtin_amdgcn_exp2f(x);
#else
  float r;
  asm("v_exp_f32 %0, %1" : "=v"(r) : "v"(x));
  return r;
#endif
}

__device__ __forceinline__ f32x16 zero16() {
  f32x16 v;
#pragma unroll
  for (int i = 0; i < 16; ++i) v[i] = 0.f;
  return v;
}

// ---------------- prep kernels ----------------
__global__ __launch_bounds__(256) void k_prep_x(const float* __restrict__ x, bf16* __restrict__ xb) {
  int gid = blockIdx.x * 256 + threadIdx.x;
  const f32x4* xv = (const f32x4*)x;
  f32x4 a = xv[(size_t)gid * 2], b = xv[(size_t)gid * 2 + 1];
  bf16x8 o;
#pragma unroll
  for (int i = 0; i < 4; ++i) { o[i] = (bf16)a[i]; o[i + 4] = (bf16)b[i]; }
  *(bf16x8*)(xb + (size_t)gid * 8) = o;
}

// LDS-tiled transpose: W[1024][C] f32 -> WT[C'][1024] bf16 (coalesced reads, full-line writes).
// MODE 0: C=3072, j = permuted qkv column, Q-columns (which==0) pre-scaled by QSCALE.
// MODE 1: C=1024, j = c.
template <int MODE>
__global__ __launch_bounds__(256) void k_prep_w(const float* __restrict__ W, bf16* __restrict__ WT) {
  __shared__ float tile[64][256];
  const int C = (MODE == 0) ? 3072 : 1024;
  const int c0 = blockIdx.x * 256, k0 = blockIdx.y * 64;
  const int lw = threadIdx.x & 63, w = threadIdx.x >> 6;
#pragma unroll
  for (int i = 0; i < 16; ++i) {
    int r = i * 4 + w;
    f32x4 v = *(const f32x4*)(W + (size_t)(k0 + r) * C + c0 + lw * 4);
    *(f32x4*)&tile[r][lw * 4] = v;
  }
  __syncthreads();
  const int c = c0 + threadIdx.x;
  int j;
  float sc = 1.0f;
  if (MODE == 0) {
    int h = c / 192, rem = c - h * 192, dd = rem / 3, wh = rem - dd * 3;
    j = wh * 1024 + h * 64 + dd;
    if (wh == 0) sc = QSCALE;
  } else {
    j = c;
  }
#pragma unroll
  for (int ch = 0; ch < 8; ++ch) {
    bf16x8 o;
#pragma unroll
    for (int i = 0; i < 8; ++i) o[i] = (bf16)(tile[ch * 8 + i][threadIdx.x] * sc);
    *(bf16x8*)(WT + (size_t)j * 1024 + k0 + ch * 8) = o;
  }
}

__global__ __launch_bounds__(256) void k_prep_bias(const float* __restrict__ bqkv, float* __restrict__ bp) {
  int gid = blockIdx.x * 256 + threadIdx.x;  // gid = j in [0,3072)
  int wj = gid >> 10, rr = gid & 1023, hh = rr >> 6, d2 = rr & 63;
  float v = bqkv[hh * 192 + d2 * 3 + wj];
  bp[gid] = (wj == 0) ? v * QSCALE : v;
}

// ---------------- 128x128 GEMM, K=1024: C = A[M][1024] @ BT[N][1024]^T + bias ----------------
// EPI 0: Q/K -> [b,h,n,64] bf16 (qk base, K at +4194304); V -> VT [b,h,64,n] bf16 (fused transpose)
// EPI 1: fp32 out[M][1024] + bias
template <int EPI>
__global__ __launch_bounds__(256) void k_gemm(const bf16* __restrict__ A, const bf16* __restrict__ BT,
                                              const float* __restrict__ bias, bf16* __restrict__ qk,
                                              bf16* __restrict__ vt, float* __restrict__ outf) {
  __shared__ __align__(16) unsigned char sA[16384];
  __shared__ __align__(16) unsigned char sB[16384];
  const int tid = threadIdx.x;
  const int l = tid & 63, w = tid >> 6, g = l >> 4, l15 = l & 15;
  const int wr = w >> 1, wc = w & 1;
  const int bm = blockIdx.y, bn = blockIdx.x;
  const unsigned char* Ab = (const unsigned char*)A + (size_t)bm * 128 * 2048;
  const unsigned char* Bb = (const unsigned char*)BT + (size_t)bn * 128 * 2048;
  f32x4 acc[4][4];
#pragma unroll
  for (int mi = 0; mi < 4; ++mi)
#pragma unroll
    for (int ni = 0; ni < 4; ++ni) acc[mi][ni] = (f32x4){0.f, 0.f, 0.f, 0.f};

  for (int kt = 0; kt < 16; ++kt) {
    const int k0b = kt * 128;  // 64 bf16 = 128 bytes per K-tile
#pragma unroll
    for (int p = 0; p < 4; ++p) {
      int co = (p * 256 + tid) * 16;
      int row = co >> 7, wb = co & 127;
      int sw = wb ^ ((row & 7) << 4);  // pre-swizzled global source, linear LDS dest
      glds16(Ab + (size_t)row * 2048 + k0b + sw, sA + co);
      glds16(Bb + (size_t)row * 2048 + k0b + sw, sB + co);
    }
    __syncthreads();
#pragma unroll
    for (int ks = 0; ks < 2; ++ks) {
      bf16x8 af[4], bfr[4];
#pragma unroll
      for (int mi = 0; mi < 4; ++mi) af[mi] = ldsfrag(sA, wr * 64 + mi * 16 + l15, ks * 64 + g * 16);
#pragma unroll
      for (int ni = 0; ni < 4; ++ni) bfr[ni] = ldsfrag(sB, wc * 64 + ni * 16 + l15, ks * 64 + g * 16);
      __builtin_amdgcn_s_setprio(1);
#pragma unroll
      for (int mi = 0; mi < 4; ++mi)
#pragma unroll
        for (int ni = 0; ni < 4; ++ni) acc[mi][ni] = MFMA16(af[mi], bfr[ni], acc[mi][ni]);
      __builtin_amdgcn_s_setprio(0);
    }
    __syncthreads();
  }
#pragma unroll
  for (int ni = 0; ni < 4; ++ni) {
    int j = bn * 128 + wc * 64 + ni * 16 + l15;
    float bj = bias[j];
#pragma unroll
    for (int mi = 0; mi < 4; ++mi) {
      int m0 = bm * 128 + wr * 64 + mi * 16 + g * 4;  // C/D: row=(l>>4)*4+reg, col=l&15
      float v[4];
#pragma unroll
      for (int rr = 0; rr < 4; ++rr) v[rr] = acc[mi][ni][rr] + bj;
      if (EPI == 0) {
        int which = j >> 10, r = j & 1023, h = r >> 6, dd = r & 63;
        int b = m0 >> 11, nn = m0 & 2047;
        if (which < 2) {
#pragma unroll
          for (int rr = 0; rr < 4; ++rr)
            qk[(size_t)which * 4194304 + (((size_t)b * 16 + h) * 2048 + nn + rr) * 64 + dd] = (bf16)v[rr];
        } else {
          bf16x4 pw = {(bf16)v[0], (bf16)v[1], (bf16)v[2], (bf16)v[3]};
          *(bf16x4*)(vt + (((size_t)b * 16 + h) * 64 + dd) * 2048 + nn) = pw;
        }
      } else {
#pragma unroll
        for (int rr = 0; rr < 4; ++rr) outf[(size_t)(m0 + rr) * 1024 + j] = v[rr];
      }
    }
  }
}

// ---------------- flash attention: r13 = r12 counted-vmcnt skeleton + r9 register budget ----------
// r12 post-mortem: skeleton correct (canary held) but pbA/pbB double-buffer (+32 VGPR) hit the
// 128-VGPR wall -> spill (46MB scratch). pb double-buffering was NEVER needed: ITER does
// PV(pb) THEN QK->pb, a read-then-overwrite on one buffer (r9 did exactly this at VGPR 116).
// r13 = r12 with single pb[2][4]. Everything else identical: K,V triple-buffered, stage
// K(t+3)/V(t+2) at iter t, s_waitcnt vmcnt(4) + raw s_barrier (T4: loop never drains to 0),
// sched_barrier(0) fences (rule #18), period-6 unroll for compile-time buffer indices.
// FP stream identical to r9 -> absmax must stay exactly 9.766e-4.
__global__ __launch_bounds__(512, 1) void k_attn(const bf16* __restrict__ Qg, const bf16* __restrict__ Kg,
                                                 const bf16* __restrict__ VTg, bf16* __restrict__ Og) {
  // [0,49152): K tiles [grp][3 bufs][8192]      (epilogue: mbuf, 64KB spans K+V regions)
  // [49152,98304): V tiles [grp][3 bufs][8192]  (epilogue: sO per g0-wave at +65536)
  // [98304,100352): lsum merge buf [4 waves][2 qt][64] f32
  __shared__ __align__(16) unsigned char smem[100352];
  const int tid = threadIdx.x;
  const int l = tid & 63, w = tid >> 6;
  const int q = l & 31, hi = l >> 5;
  const int g = w >> 2, wl = w & 3;
  const int stid = tid & 255;

  const int bid = blockIdx.x;                  // 256 blocks
  const int wg = (bid & 7) * 32 + (bid >> 3);  // XCD-chunked: 4 consecutive bh per XCD
  const int bh = wg >> 3;
  const int q0w = (wg & 7) * 256 + wl * 64;    // this wave's 64 q-rows

  // Q B-fragments (Q pre-scaled by log2e/32): qf[qt][ks] = Q[q0w+qt*32+q][ks*16 + hi*8 + j]
  bf16x8 qf[2][4];
#pragma unroll
  for (int qt = 0; qt < 2; ++qt)
#pragma unroll
    for (int ks = 0; ks < 4; ++ks)
      qf[qt][ks] = *(const bf16x8*)(Qg + ((size_t)bh * 2048 + q0w + qt * 32 + q) * 64 + ks * 16 + hi * 8);

  f32x16 oacc[2][2];  // [qt][dt] O^T[dd][q]: col q = l&31, row dd = dt*32 + (reg&3)+8*(reg>>2)+4*hi
#pragma unroll
  for (int qt = 0; qt < 2; ++qt) { oacc[qt][0] = zero16(); oacc[qt][1] = zero16(); }
  float lrun4[2][4] = {{0.f, 0.f, 0.f, 0.f}, {0.f, 0.f, 0.f, 0.f}};
  bf16x8 pb[2][4];  // packed P of the pending tile (single buffer: PV reads, then QK overwrites)

  const unsigned char* Kb = (const unsigned char*)Kg + (size_t)bh * 262144 + (size_t)g * 131072;
  const unsigned char* Vb = (const unsigned char*)VTg + (size_t)bh * 262144 + (size_t)g * 2048;
  unsigned char* sKg = smem + g * 24576;
  unsigned char* sVg = smem + 49152 + g * 24576;

  // per-thread staging coords (loop-invariant)
  const int co0 = stid * 16, co1 = (256 + stid) * 16;
  const int row0 = co0 >> 7, row1 = co1 >> 7;
  const int sw0 = (co0 & 127) ^ ((row0 & 7) << 4), sw1 = (co1 & 127) ^ ((row1 & 7) << 4);

#define STAGE_K(kb_, buf_)                                                        \
  do {                                                                            \
    const unsigned char* Ksrc = Kb + (size_t)(kb_) * 8192;                        \
    glds16(Ksrc + (co0 & ~127) + sw0, sKg + (buf_) * 8192 + co0);                 \
    glds16(Ksrc + (co1 & ~127) + sw1, sKg + (buf_) * 8192 + co1);                 \
  } while (0)
#define STAGE_V(kb_, buf_)                                                        \
  do {                                                                            \
    glds16(Vb + (size_t)row0 * 4096 + (size_t)(kb_) * 128 + sw0, sVg + (buf_) * 8192 + co0); \
    glds16(Vb + (size_t)row1 * 4096 + (size_t)(kb_) * 128 + sw1, sVg + (buf_) * 8192 + co1); \
  } while (0)

// counted vmem wait + raw barrier (T4): this iter's stages stay in flight
#define VMWAIT(n)                                                                 \
  do {                                                                            \
    asm volatile("s_waitcnt vmcnt(" #n ")" ::: "memory");                         \
    __builtin_amdgcn_sched_barrier(0);                                            \
  } while (0)
#define RAWBAR()                                                                  \
  do {                                                                            \
    __builtin_amdgcn_sched_barrier(0);                                            \
    __builtin_amdgcn_s_barrier();                                                 \
    __builtin_amdgcn_sched_barrier(0);                                            \
  } while (0)

  // QK^T + exp + pack for one 64-key tile, both qt subtiles sharing the K fragments (r9 body)
#define QK_EXP_PACK(kbase_)                                                       \
  do {                                                                            \
    _Pragma("unroll") for (int kt = 0; kt < 2; ++kt) {                            \
      bf16x8 kf[4];                                                               \
      _Pragma("unroll") for (int ks = 0; ks < 4; ++ks)                            \
        kf[ks] = ldsfrag((kbase_), kt * 32 + q, ks * 32 + hi * 16);               \
      _Pragma("unroll") for (int qt = 0; qt < 2; ++qt) {                          \
        f32x16 sacc = zero16();                                                   \
        __builtin_amdgcn_s_setprio(1);                                            \
        _Pragma("unroll") for (int ks = 0; ks < 4; ++ks)                          \
          sacc = MFMA32(kf[ks], qf[qt][ks], sacc);                                \
        __builtin_amdgcn_s_setprio(0);                                            \
        float pe[16];                                                             \
        _Pragma("unroll") for (int r = 0; r < 16; ++r) pe[r] = fexp2(sacc[r]);    \
        _Pragma("unroll") for (int m = 0; m < 4; ++m)                             \
          _Pragma("unroll") for (int j = 0; j < 4; ++j) lrun4[qt][j] += pe[4 * m + j]; \
        uint32_t c[4][2];                                                         \
        _Pragma("unroll") for (int m = 0; m < 4; ++m) {                           \
          c[m][0] = pkbf16(pe[4 * m], pe[4 * m + 1]);                             \
          c[m][1] = pkbf16(pe[4 * m + 2], pe[4 * m + 3]);                         \
        }                                                                         \
        _Pragma("unroll") for (int s = 0; s < 2; ++s) {                           \
          uint32_t x0 = c[2 * s][0], y0 = c[2 * s + 1][0];                        \
          uint32_t x1 = c[2 * s][1], y1 = c[2 * s + 1][1];                        \
          asm("v_permlane32_swap_b32 %0, %1" : "+v"(x0), "+v"(y0));               \
          asm("v_permlane32_swap_b32 %0, %1" : "+v"(x1), "+v"(y1));               \
          union { uint32_t u[4]; bf16x8 v; } bfr;                                 \
          bfr.u[0] = x0; bfr.u[1] = x1; bfr.u[2] = y0; bfr.u[3] = y1;             \
          pb[qt][kt * 2 + s] = bfr.v;                                             \
        }                                                                         \
      }                                                                           \
    }                                                                             \
  } while (0)

  // PV: both qt share each V fragment (ks order 0..3 per [qt][dt] -> r9 FP order)
#define PV_TILE(vbase_)                                                           \
  do {                                                                            \
    __builtin_amdgcn_s_setprio(1);                                                \
    _Pragma("unroll") for (int ks = 0; ks < 4; ++ks)                              \
      _Pragma("unroll") for (int dt = 0; dt < 2; ++dt) {                          \
        bf16x8 vf = ldsfrag((vbase_), dt * 32 + q, ks * 32 + hi * 16);            \
        _Pragma("unroll") for (int qtp = 0; qtp < 2; ++qtp)                       \
          oacc[qtp][dt] = MFMA32(vf, pb[qtp][ks], oacc[qtp][dt]);                 \
      }                                                                           \
    __builtin_amdgcn_s_setprio(0);                                                \
  } while (0)

  // steady iter t: reads K(t+1) from buf (t+1)%3, V(t) from buf t%3;
  // stages K(t+3) -> buf t%3, V(t+2) -> buf (t+2)%3. PV reads pb, then QK overwrites pb.
#define ITER(T, KR, VR, KS, VS, DOKS, DOVS, VM)                                   \
  do {                                                                            \
    if (DOKS) STAGE_K((T) + 3, KS);                                               \
    if (DOVS) STAGE_V((T) + 2, VS);                                               \
    PV_TILE(sVg + (VR) * 8192);                                                   \
    QK_EXP_PACK(sKg + (KR) * 8192);                                               \
    VMWAIT(VM);                                                                   \
    RAWBAR();                                                                     \
  } while (0)

  // ---- prologue: stage K0,V0,K1,V1,K2 (10 loads); P(0) -> pb ----
  STAGE_K(0, 0);
  STAGE_V(0, 0);
  STAGE_K(1, 1);
  STAGE_V(1, 1);
  STAGE_K(2, 2);
  VMWAIT(6);   // K0,V0 landed (K1,V1,K2 in flight); Q-loads drained too
  RAWBAR();
  QK_EXP_PACK(sKg);  // tile 0 from K buf 0
  VMWAIT(2);   // K1,V1 landed (K2 in flight)
  RAWBAR();

  // ---- steady state t=0..14 (period-6 unroll keeps bufs compile-time) ----
  for (int t0 = 0; t0 < 12; t0 += 6) {
    ITER(t0 + 0, 1, 0, 0, 2, 1, 1, 4);
    ITER(t0 + 1, 2, 1, 1, 0, 1, 1, 4);
    ITER(t0 + 2, 0, 2, 2, 1, 1, 1, 4);
    ITER(t0 + 3, 1, 0, 0, 2, 1, 1, 4);
    ITER(t0 + 4, 2, 1, 1, 0, 1, 1, 4);
    ITER(t0 + 5, 0, 2, 2, 1, 1, 1, 4);
  }
  ITER(12, 1, 0, 0, 2, 1, 1, 4);  // stages K(15), V(14)
  ITER(13, 2, 1, 1, 0, 0, 1, 2);  // stages V(15) only
  ITER(14, 0, 2, 2, 1, 0, 0, 0);  // no stages; drain all
  PV_TILE(sVg + 0 * 8192);        // tile 15 (V15 in buf 0)

#undef STAGE_K
#undef STAGE_V
#undef VMWAIT
#undef RAWBAR
#undef QK_EXP_PACK
#undef PV_TILE
#undef ITER

  __syncthreads();  // full drain before LDS reuse (epilogue)

  float lrun[2];
#pragma unroll
  for (int qt = 0; qt < 2; ++qt)
    lrun[qt] = (lrun4[qt][0] + lrun4[qt][1]) + (lrun4[qt][2] + lrun4[qt][3]);

  // ---- merge the two KV halves (additive: no-max softmax), then transpose O^T and store ----
  float* mbuf = (float*)smem;           // [4 waves][2 qt][32 regs][64 lanes] f32 = 64KB
  float* lb = (float*)(smem + 98304);   // [4 waves][2 qt][64]
  if (g == 1) {
#pragma unroll
    for (int qt = 0; qt < 2; ++qt) {
#pragma unroll
      for (int dt = 0; dt < 2; ++dt)
#pragma unroll
        for (int r = 0; r < 16; ++r)
          mbuf[((wl * 64 + qt * 32 + dt * 16 + r) << 6) + l] = oacc[qt][dt][r];
      lb[(wl * 2 + qt) * 64 + l] = lrun[qt];
    }
  }
  __syncthreads();
  if (g == 0) {
#pragma unroll
    for (int qt = 0; qt < 2; ++qt)
#pragma unroll
      for (int dt = 0; dt < 2; ++dt)
#pragma unroll
        for (int r = 0; r < 16; ++r)
          oacc[qt][dt][r] += mbuf[((wl * 64 + qt * 32 + dt * 16 + r) << 6) + l];
  }
  __syncthreads();  // mbuf reads done before sO region reuse below
  if (g == 0) {
    const int b = bh >> 4, h = bh & 15;
    unsigned char* sO = smem + 65536 + wl * 4096;  // per-wave [32 q][64 dd] bf16, XOR-16 swizzled
#pragma unroll
    for (int qt = 0; qt < 2; ++qt) {
      float lr = lrun[qt] + lb[(wl * 2 + qt) * 64 + l];
      float ps = lr + __shfl_xor(lr, 32);
      float linv = 1.0f / ps;
#pragma unroll
      for (int dt = 0; dt < 2; ++dt)
#pragma unroll
        for (int m = 0; m < 4; ++m) {
          uint32_t b0 = pkbf16(oacc[qt][dt][4 * m] * linv, oacc[qt][dt][4 * m + 1] * linv);
          uint32_t b1 = pkbf16(oacc[qt][dt][4 * m + 2] * linv, oacc[qt][dt][4 * m + 3] * linv);
          int byteo = (dt * 64 + m * 16 + hi * 8) ^ ((q & 7) << 4);
          uint32_t* dst = (uint32_t*)(sO + q * 128 + byteo);
          dst[0] = b0; dst[1] = b1;
        }
      const int q0 = q0w + qt * 32;
#pragma unroll
      for (int rd = 0; rd < 4; ++rd) {
        int byteo = hi * 64 + rd * 16;
        bf16x8 v = *(const bf16x8*)(sO + q * 128 + (byteo ^ ((q & 7) << 4)));
        *(bf16x8*)(Og + ((size_t)b * 2048 + q0 + q) * 1024 + h * 64 + byteo / 2) = v;
      }
    }
  }
}

extern "C" void kernel_launch(void* const* d_in, const int* in_sizes, int n_in,
                              void* d_out, int out_size, void* d_ws, size_t ws_size,
                              hipStream_t stream) {
  const float* x = (const float*)d_in[0];
  const float* Wqkv = (const float*)d_in[1];
  const float* bqkv = (const float*)d_in[2];
  const float* Wproj = (const float*)d_in[3];
  const float* bproj = (const float*)d_in[4];
  float* out = (float*)d_out;
  char* ws = (char*)d_ws;

  bf16* XB = (bf16*)(ws + 0);            // 8 MB x_bf16 [4096][1024]; reused as attn-out
  bf16* WQT = (bf16*)(ws + 8388608);     // 6 MB WqkvT (permuted, Q pre-scaled) [3072][1024]
  float* BQP = (float*)(ws + 14680064);  // 16 KB permuted bias (Q part pre-scaled)
  bf16* WPT = (bf16*)(ws + 14696448);    // 2 MB WprojT [1024][1024]
  bf16* Q = (bf16*)(ws + 16793600);      // 8 MB [2][16][2048][64]
  bf16* K = (bf16*)(ws + 25182208);      // 8 MB (contiguous after Q: qk base + 4194304 elems)
  bf16* VT = (bf16*)(ws + 33570816);     // 8 MB [2][16][64][2048] (written directly by gemm<0>)
  bf16* AO = XB;
  (void)K;
  (void)ws_size;

  k_prep_x<<<2048, 256, 0, stream>>>(x, XB);
  k_prep_w<0><<<dim3(12, 16), 256, 0, stream>>>(Wqkv, WQT);
  k_prep_w<1><<<dim3(4, 16), 256, 0, stream>>>(Wproj, WPT);
  k_prep_bias<<<12, 256, 0, stream>>>(bqkv, BQP);
  k_gemm<0><<<dim3(24, 32), 256, 0, stream>>>(XB, WQT, BQP, Q, VT, nullptr);
  k_attn<<<256, 512, 0, stream>>>(Q, Q + 4194304, VT, AO);
  k_gemm<1><<<dim3(8, 32), 256, 0, stream>>>(AO, WPT, bproj, nullptr, nullptr, out);
}

// Round 14
// 117.282 us; speedup vs baseline: 1.1915x; 1.1896x over previous
//
#include <hip/hip_runtime.h>
#include <hip/hip_bf16.h>
#include <stdint.h>

typedef __bf16 bf16;
typedef __attribute__((ext_vector_type(8))) __bf16 bf16x8;
typedef __attribute__((ext_vector_type(4))) __bf16 bf16x4;
typedef __attribute__((ext_vector_type(4))) float f32x4;
typedef __attribute__((ext_vector_type(16))) float f32x16;

#define MFMA16(a, b, c) __builtin_amdgcn_mfma_f32_16x16x32_bf16((a), (b), (c), 0, 0, 0)
#define MFMA32(a, b, c) __builtin_amdgcn_mfma_f32_32x32x16_bf16((a), (b), (c), 0, 0, 0)

// log2(e) / sqrt(1024)
#define QSCALE 0.045084220027780106f

__device__ __forceinline__ void glds16(const void* g, void* l) {
  __builtin_amdgcn_global_load_lds(
      (const __attribute__((address_space(1))) void*)g,
      (__attribute__((address_space(3))) void*)l, 16, 0, 0);
}

// swizzled 16B fragment read from a [rows][64] bf16 tile (128B rows, XOR-16 swizzle)
__device__ __forceinline__ bf16x8 ldsfrag(const unsigned char* base, int row, int colb) {
  return *(const bf16x8*)(base + row * 128 + (colb ^ ((row & 7) << 4)));
}

__device__ __forceinline__ uint32_t pkbf16(float a, float b) {
  uint32_t r;
  asm("v_cvt_pk_bf16_f32 %0, %1, %2" : "=v"(r) : "v"(a), "v"(b));
  return r;
}

// raw v_exp_f32: args here are far from the subnormal range, skip libm's fixup
__device__ __forceinline__ float fexp2(float x) {
#if __has_builtin(__builtin_amdgcn_exp2f)
  return __builtin_amdgcn_exp2f(x);
#else
  float r;
  asm("v_exp_f32 %0, %1" : "=v"(r) : "v"(x));
  return r;
#endif
}

__device__ __forceinline__ f32x16 zero16() {
  f32x16 v;
#pragma unroll
  for (int i = 0; i < 16; ++i) v[i] = 0.f;
  return v;
}

// ---------------- fused prep kernel (r14): all 4 preps in one dispatch ----------------
// blocks [0,2048): x f32 -> bf16
// blocks [2048,2240): Wqkv LDS-tiled transpose+permute (192 = 12 c-tiles x 16 k-tiles)
// blocks [2240,2304): Wproj LDS-tiled transpose (64 = 4 x 16)
// blocks [2304,2316): bias permute (12)
// All independent; fusing removes 3 launch gaps and overlaps the memory-bound phases.
template <int MODE>
__device__ __forceinline__ void prep_w_body(const float* __restrict__ W, bf16* __restrict__ WT,
                                            float (*tile)[256], int c0, int k0) {
  const int C = (MODE == 0) ? 3072 : 1024;
  const int lw = threadIdx.x & 63, w = threadIdx.x >> 6;
#pragma unroll
  for (int i = 0; i < 16; ++i) {
    int r = i * 4 + w;
    f32x4 v = *(const f32x4*)(W + (size_t)(k0 + r) * C + c0 + lw * 4);
    *(f32x4*)&tile[r][lw * 4] = v;
  }
  __syncthreads();
  const int c = c0 + threadIdx.x;
  int j;
  float sc = 1.0f;
  if (MODE == 0) {
    int h = c / 192, rem = c - h * 192, dd = rem / 3, wh = rem - dd * 3;
    j = wh * 1024 + h * 64 + dd;
    if (wh == 0) sc = QSCALE;
  } else {
    j = c;
  }
#pragma unroll
  for (int ch = 0; ch < 8; ++ch) {
    bf16x8 o;
#pragma unroll
    for (int i = 0; i < 8; ++i) o[i] = (bf16)(tile[ch * 8 + i][threadIdx.x] * sc);
    *(bf16x8*)(WT + (size_t)j * 1024 + k0 + ch * 8) = o;
  }
}

__global__ __launch_bounds__(256) void k_prep_all(const float* __restrict__ x,
                                                  const float* __restrict__ Wqkv,
                                                  const float* __restrict__ bqkv,
                                                  const float* __restrict__ Wproj,
                                                  bf16* __restrict__ xb, bf16* __restrict__ WQT,
                                                  bf16* __restrict__ WPT, float* __restrict__ bp) {
  __shared__ float tile[64][256];
  int bid = blockIdx.x;
  if (bid < 2048) {  // ---- x -> bf16 ----
    int gid = bid * 256 + threadIdx.x;
    const f32x4* xv = (const f32x4*)x;
    f32x4 a = xv[(size_t)gid * 2], b = xv[(size_t)gid * 2 + 1];
    bf16x8 o;
#pragma unroll
    for (int i = 0; i < 4; ++i) { o[i] = (bf16)a[i]; o[i + 4] = (bf16)b[i]; }
    *(bf16x8*)(xb + (size_t)gid * 8) = o;
    return;
  }
  bid -= 2048;
  if (bid < 192) {  // ---- Wqkv transpose+permute ----
    prep_w_body<0>(Wqkv, WQT, tile, (bid % 12) * 256, (bid / 12) * 64);
    return;
  }
  bid -= 192;
  if (bid < 64) {  // ---- Wproj transpose ----
    prep_w_body<1>(Wproj, WPT, tile, (bid % 4) * 256, (bid / 4) * 64);
    return;
  }
  bid -= 64;
  {  // ---- bias permute (12 blocks) ----
    int gid = bid * 256 + threadIdx.x;  // j in [0,3072)
    int wj = gid >> 10, rr = gid & 1023, hh = rr >> 6, d2 = rr & 63;
    float v = bqkv[hh * 192 + d2 * 3 + wj];
    bp[gid] = (wj == 0) ? v * QSCALE : v;
  }
}

// ---------------- 128x128 GEMM, K=1024: C = A[M][1024] @ BT[N][1024]^T + bias ----------------
// EPI 0: Q/K -> [b,h,n,64] bf16 (qk base, K at +4194304); V -> VT [b,h,64,n] bf16 (fused transpose)
// EPI 1: fp32 out[M][1024] + bias
template <int EPI>
__global__ __launch_bounds__(256) void k_gemm(const bf16* __restrict__ A, const bf16* __restrict__ BT,
                                              const float* __restrict__ bias, bf16* __restrict__ qk,
                                              bf16* __restrict__ vt, float* __restrict__ outf) {
  __shared__ __align__(16) unsigned char sA[16384];
  __shared__ __align__(16) unsigned char sB[16384];
  const int tid = threadIdx.x;
  const int l = tid & 63, w = tid >> 6, g = l >> 4, l15 = l & 15;
  const int wr = w >> 1, wc = w & 1;
  const int bm = blockIdx.y, bn = blockIdx.x;
  const unsigned char* Ab = (const unsigned char*)A + (size_t)bm * 128 * 2048;
  const unsigned char* Bb = (const unsigned char*)BT + (size_t)bn * 128 * 2048;
  f32x4 acc[4][4];
#pragma unroll
  for (int mi = 0; mi < 4; ++mi)
#pragma unroll
    for (int ni = 0; ni < 4; ++ni) acc[mi][ni] = (f32x4){0.f, 0.f, 0.f, 0.f};

  for (int kt = 0; kt < 16; ++kt) {
    const int k0b = kt * 128;  // 64 bf16 = 128 bytes per K-tile
#pragma unroll
    for (int p = 0; p < 4; ++p) {
      int co = (p * 256 + tid) * 16;
      int row = co >> 7, wb = co & 127;
      int sw = wb ^ ((row & 7) << 4);  // pre-swizzled global source, linear LDS dest
      glds16(Ab + (size_t)row * 2048 + k0b + sw, sA + co);
      glds16(Bb + (size_t)row * 2048 + k0b + sw, sB + co);
    }
    __syncthreads();
#pragma unroll
    for (int ks = 0; ks < 2; ++ks) {
      bf16x8 af[4], bfr[4];
#pragma unroll
      for (int mi = 0; mi < 4; ++mi) af[mi] = ldsfrag(sA, wr * 64 + mi * 16 + l15, ks * 64 + g * 16);
#pragma unroll
      for (int ni = 0; ni < 4; ++ni) bfr[ni] = ldsfrag(sB, wc * 64 + ni * 16 + l15, ks * 64 + g * 16);
      __builtin_amdgcn_s_setprio(1);
#pragma unroll
      for (int mi = 0; mi < 4; ++mi)
#pragma unroll
        for (int ni = 0; ni < 4; ++ni) acc[mi][ni] = MFMA16(af[mi], bfr[ni], acc[mi][ni]);
      __builtin_amdgcn_s_setprio(0);
    }
    __syncthreads();
  }
#pragma unroll
  for (int ni = 0; ni < 4; ++ni) {
    int j = bn * 128 + wc * 64 + ni * 16 + l15;
    float bj = bias[j];
#pragma unroll
    for (int mi = 0; mi < 4; ++mi) {
      int m0 = bm * 128 + wr * 64 + mi * 16 + g * 4;  // C/D: row=(l>>4)*4+reg, col=l&15
      float v[4];
#pragma unroll
      for (int rr = 0; rr < 4; ++rr) v[rr] = acc[mi][ni][rr] + bj;
      if (EPI == 0) {
        int which = j >> 10, r = j & 1023, h = r >> 6, dd = r & 63;
        int b = m0 >> 11, nn = m0 & 2047;
        if (which < 2) {
#pragma unroll
          for (int rr = 0; rr < 4; ++rr)
            qk[(size_t)which * 4194304 + (((size_t)b * 16 + h) * 2048 + nn + rr) * 64 + dd] = (bf16)v[rr];
        } else {
          bf16x4 pw = {(bf16)v[0], (bf16)v[1], (bf16)v[2], (bf16)v[3]};
          *(bf16x4*)(vt + (((size_t)b * 16 + h) * 64 + dd) * 2048 + nn) = pw;
        }
      } else {
#pragma unroll
        for (int rr = 0; rr < 4; ++rr) outf[(size_t)(m0 + rr) * 1024 + j] = v[rr];
      }
    }
  }
}

// ---------------- flash attention: 32x32 MFMA, 64 q/wave, in-register P, KV-split 2 groups --------
// r14 = exact r9 kernel (best proven: ~50us, VGPR 116, no spill). r11/r12/r13 experiments
// (interleave, counted-vmcnt skeletons) all spilled past the 128-VGPR wall -> closed.
// 256 blocks x 8 waves; each wave owns 64 q (2 subtiles of 32). K/V LDS fragments depend only on
// (lane, k-slice) so each ds_read_b128 feeds 2x MFMA work. PV(kb) || QK(kb+1) pipeline,
// K+V double-buffered glds16, 1 barrier/tile. absmax canary: exactly 9.766e-4.
__global__ __launch_bounds__(512, 1) void k_attn(const bf16* __restrict__ Qg, const bf16* __restrict__ Kg,
                                                 const bf16* __restrict__ VTg, bf16* __restrict__ Og) {
  // [0,32768): K tiles [grp][buf][8192]      (epilogue: mbuf low half)
  // [32768,65536): V tiles [grp][buf][8192]  (epilogue: mbuf high half; sO after 2nd barrier)
  // [65536,67584): lsum merge buf [8][64] f32
  __shared__ __align__(16) unsigned char smem[67584];
  const int tid = threadIdx.x;
  const int l = tid & 63, w = tid >> 6;
  const int q = l & 31, hi = l >> 5;
  const int g = w >> 2, wl = w & 3;
  const int stid = tid & 255;

  const int bid = blockIdx.x;                  // 256 blocks
  const int wg = (bid & 7) * 32 + (bid >> 3);  // XCD-chunked: 4 consecutive bh per XCD
  const int bh = wg >> 3;
  const int q0w = (wg & 7) * 256 + wl * 64;    // this wave's 64 q-rows

  // Q B-fragments (Q pre-scaled by log2e/32): qf[qt][ks] = Q[q0w+qt*32+q][ks*16 + hi*8 + j]
  bf16x8 qf[2][4];
#pragma unroll
  for (int qt = 0; qt < 2; ++qt)
#pragma unroll
    for (int ks = 0; ks < 4; ++ks)
      qf[qt][ks] = *(const bf16x8*)(Qg + ((size_t)bh * 2048 + q0w + qt * 32 + q) * 64 + ks * 16 + hi * 8);

  f32x16 oacc[2][2];  // [qt][dt] O^T[dd][q]: col q = l&31, row dd = dt*32 + (reg&3)+8*(reg>>2)+4*hi
#pragma unroll
  for (int qt = 0; qt < 2; ++qt) { oacc[qt][0] = zero16(); oacc[qt][1] = zero16(); }
  float lrun4[2][4] = {{0.f, 0.f, 0.f, 0.f}, {0.f, 0.f, 0.f, 0.f}};
  bf16x8 pb[2][4];  // packed P of the pending tile, per qt

  const unsigned char* Kb = (const unsigned char*)Kg + (size_t)bh * 262144 + (size_t)g * 131072;
  const unsigned char* Vb = (const unsigned char*)VTg + (size_t)bh * 262144 + (size_t)g * 2048;
  unsigned char* sKg = smem + g * 16384;
  unsigned char* sVg = smem + 32768 + g * 16384;

  // per-thread staging coords (loop-invariant)
  const int co0 = stid * 16, co1 = (256 + stid) * 16;
  const int row0 = co0 >> 7, row1 = co1 >> 7;
  const int sw0 = (co0 & 127) ^ ((row0 & 7) << 4), sw1 = (co1 & 127) ^ ((row1 & 7) << 4);

#define STAGE_K(kb_, buf_)                                                        \
  do {                                                                            \
    const unsigned char* Ksrc = Kb + (size_t)(kb_) * 8192;                        \
    glds16(Ksrc + (co0 & ~127) + sw0, sKg + (buf_) * 8192 + co0);                 \
    glds16(Ksrc + (co1 & ~127) + sw1, sKg + (buf_) * 8192 + co1);                 \
  } while (0)
#define STAGE_V(kb_, buf_)                                                        \
  do {                                                                            \
    glds16(Vb + (size_t)row0 * 4096 + (size_t)(kb_) * 128 + sw0, sVg + (buf_) * 8192 + co0); \
    glds16(Vb + (size_t)row1 * 4096 + (size_t)(kb_) * 128 + sw1, sVg + (buf_) * 8192 + co1); \
  } while (0)

  // QK^T + exp + pack for one 64-key tile, both qt subtiles sharing the K fragments
#define QK_EXP_PACK(kbase_)                                                       \
  do {                                                                            \
    _Pragma("unroll") for (int kt = 0; kt < 2; ++kt) {                            \
      bf16x8 kf[4];                                                               \
      _Pragma("unroll") for (int ks = 0; ks < 4; ++ks)                            \
        kf[ks] = ldsfrag((kbase_), kt * 32 + q, ks * 32 + hi * 16);               \
      _Pragma("unroll") for (int qt = 0; qt < 2; ++qt) {                          \
        f32x16 sacc = zero16();                                                   \
        __builtin_amdgcn_s_setprio(1);                                            \
        _Pragma("unroll") for (int ks = 0; ks < 4; ++ks)                          \
          sacc = MFMA32(kf[ks], qf[qt][ks], sacc);                                \
        __builtin_amdgcn_s_setprio(0);                                            \
        float pe[16];                                                             \
        _Pragma("unroll") for (int r = 0; r < 16; ++r) pe[r] = fexp2(sacc[r]);    \
        _Pragma("unroll") for (int m = 0; m < 4; ++m)                             \
          _Pragma("unroll") for (int j = 0; j < 4; ++j) lrun4[qt][j] += pe[4 * m + j]; \
        uint32_t c[4][2];                                                         \
        _Pragma("unroll") for (int m = 0; m < 4; ++m) {                           \
          c[m][0] = pkbf16(pe[4 * m], pe[4 * m + 1]);                             \
          c[m][1] = pkbf16(pe[4 * m + 2], pe[4 * m + 3]);                         \
        }                                                                         \
        _Pragma("unroll") for (int s = 0; s < 2; ++s) {                           \
          uint32_t x0 = c[2 * s][0], y0 = c[2 * s + 1][0];                        \
          uint32_t x1 = c[2 * s][1], y1 = c[2 * s + 1][1];                        \
          asm("v_permlane32_swap_b32 %0, %1" : "+v"(x0), "+v"(y0));               \
          asm("v_permlane32_swap_b32 %0, %1" : "+v"(x1), "+v"(y1));               \
          union { uint32_t u[4]; bf16x8 v; } bfr;                                 \
          bfr.u[0] = x0; bfr.u[1] = x1; bfr.u[2] = y0; bfr.u[3] = y1;             \
          pb[qt][kt * 2 + s] = bfr.v;                                             \
        }                                                                         \
      }                                                                           \
    }                                                                             \
  } while (0)

  // PV: both qt share each V fragment (ks order 0..3 per [qt][dt])
#define PV_TILE(vbase_)                                                           \
  do {                                                                            \
    __builtin_amdgcn_s_setprio(1);                                                \
    _Pragma("unroll") for (int ks = 0; ks < 4; ++ks)                              \
      _Pragma("unroll") for (int dt = 0; dt < 2; ++dt) {                          \
        bf16x8 vf = ldsfrag((vbase_), dt * 32 + q, ks * 32 + hi * 16);            \
        _Pragma("unroll") for (int qtp = 0; qtp < 2; ++qtp)                       \
          oacc[qtp][dt] = MFMA32(vf, pb[qtp][ks], oacc[qtp][dt]);                 \
      }                                                                           \
    __builtin_amdgcn_s_setprio(0);                                                \
  } while (0)

  // ---- prologue: land K0+V0, compute P(0), land K1 ----
  STAGE_K(0, 0);
  STAGE_V(0, 0);
  __syncthreads();
  STAGE_K(1, 1);
  QK_EXP_PACK(sKg);  // tile 0 from K buf 0
  __syncthreads();   // K1 landed
  int cur = 0;

  // ---- steady state: PV(kb) || QK(kb+1), one barrier per tile ----
  for (int kb = 0; kb < 15; ++kb) {
    const int nxt = cur ^ 1;
    if (kb < 14) STAGE_K(kb + 2, cur);  // K(kb) buffer free (read finished last iter)
    STAGE_V(kb + 1, nxt);               // V(kb) in cur being read this iter
    PV_TILE(sVg + cur * 8192);          // consumes pb = P(kb)
    QK_EXP_PACK(sKg + nxt * 8192);      // produces pb = P(kb+1)
    __syncthreads();                    // drains stages; all waves done with cur-buffers
    cur = nxt;
  }
  PV_TILE(sVg + cur * 8192);  // tile 15

#undef STAGE_K
#undef STAGE_V
#undef QK_EXP_PACK
#undef PV_TILE

  float lrun[2];
#pragma unroll
  for (int qt = 0; qt < 2; ++qt)
    lrun[qt] = (lrun4[qt][0] + lrun4[qt][1]) + (lrun4[qt][2] + lrun4[qt][3]);

  // ---- merge the two KV halves (additive: no-max softmax), then transpose O^T and store ----
  float* mbuf = (float*)smem;          // [4 waves][2 qt][32 regs][64 lanes] f32 = 64KB over K+V tiles
  float* lb = (float*)(smem + 65536);  // [4 waves][2 qt][64]
  if (g == 1) {
#pragma unroll
    for (int qt = 0; qt < 2; ++qt) {
#pragma unroll
      for (int dt = 0; dt < 2; ++dt)
#pragma unroll
        for (int r = 0; r < 16; ++r)
          mbuf[((wl * 64 + qt * 32 + dt * 16 + r) << 6) + l] = oacc[qt][dt][r];
      lb[(wl * 2 + qt) * 64 + l] = lrun[qt];
    }
  }
  __syncthreads();
  if (g == 0) {
#pragma unroll
    for (int qt = 0; qt < 2; ++qt)
#pragma unroll
      for (int dt = 0; dt < 2; ++dt)
#pragma unroll
        for (int r = 0; r < 16; ++r)
          oacc[qt][dt][r] += mbuf[((wl * 64 + qt * 32 + dt * 16 + r) << 6) + l];
  }
  __syncthreads();  // all mbuf reads done before sO (32768..49152) overwrites that region
  if (g == 0) {
    const int b = bh >> 4, h = bh & 15;
    unsigned char* sO = smem + 32768 + wl * 4096;  // per-wave [32 q][64 dd] bf16, XOR-16 swizzled
#pragma unroll
    for (int qt = 0; qt < 2; ++qt) {
      float lr = lrun[qt] + lb[(wl * 2 + qt) * 64 + l];
      float ps = lr + __shfl_xor(lr, 32);
      float linv = 1.0f / ps;
#pragma unroll
      for (int dt = 0; dt < 2; ++dt)
#pragma unroll
        for (int m = 0; m < 4; ++m) {
          uint32_t b0 = pkbf16(oacc[qt][dt][4 * m] * linv, oacc[qt][dt][4 * m + 1] * linv);
          uint32_t b1 = pkbf16(oacc[qt][dt][4 * m + 2] * linv, oacc[qt][dt][4 * m + 3] * linv);
          int byteo = (dt * 64 + m * 16 + hi * 8) ^ ((q & 7) << 4);
          uint32_t* dst = (uint32_t*)(sO + q * 128 + byteo);
          dst[0] = b0; dst[1] = b1;
        }
      const int q0 = q0w + qt * 32;
#pragma unroll
      for (int rd = 0; rd < 4; ++rd) {
        int byteo = hi * 64 + rd * 16;
        bf16x8 v = *(const bf16x8*)(sO + q * 128 + (byteo ^ ((q & 7) << 4)));
        *(bf16x8*)(Og + ((size_t)b * 2048 + q0 + q) * 1024 + h * 64 + byteo / 2) = v;
      }
    }
  }
}

extern "C" void kernel_launch(void* const* d_in, const int* in_sizes, int n_in,
                              void* d_out, int out_size, void* d_ws, size_t ws_size,
                              hipStream_t stream) {
  const float* x = (const float*)d_in[0];
  const float* Wqkv = (const float*)d_in[1];
  const float* bqkv = (const float*)d_in[2];
  const float* Wproj = (const float*)d_in[3];
  const float* bproj = (const float*)d_in[4];
  float* out = (float*)d_out;
  char* ws = (char*)d_ws;

  bf16* XB = (bf16*)(ws + 0);            // 8 MB x_bf16 [4096][1024]; reused as attn-out
  bf16* WQT = (bf16*)(ws + 8388608);     // 6 MB WqkvT (permuted, Q pre-scaled) [3072][1024]
  float* BQP = (float*)(ws + 14680064);  // 16 KB permuted bias (Q part pre-scaled)
  bf16* WPT = (bf16*)(ws + 14696448);    // 2 MB WprojT [1024][1024]
  bf16* Q = (bf16*)(ws + 16793600);      // 8 MB [2][16][2048][64]
  bf16* K = (bf16*)(ws + 25182208);      // 8 MB (contiguous after Q: qk base + 4194304 elems)
  bf16* VT = (bf16*)(ws + 33570816);     // 8 MB [2][16][64][2048] (written directly by gemm<0>)
  bf16* AO = XB;
  (void)K;
  (void)ws_size;

  k_prep_all<<<2316, 256, 0, stream>>>(x, Wqkv, bqkv, Wproj, XB, WQT, WPT, BQP);
  k_gemm<0><<<dim3(24, 32), 256, 0, stream>>>(XB, WQT, BQP, Q, VT, nullptr);
  k_attn<<<256, 512, 0, stream>>>(Q, Q + 4194304, VT, AO);
  k_gemm<1><<<dim3(8, 32), 256, 0, stream>>>(AO, WPT, bproj, nullptr, nullptr, out);
}

// Round 15
// 114.234 us; speedup vs baseline: 1.2233x; 1.0267x over previous
//
#include <hip/hip_runtime.h>
#include <hip/hip_bf16.h>
#include <stdint.h>

typedef __bf16 bf16;
typedef __attribute__((ext_vector_type(8))) __bf16 bf16x8;
typedef __attribute__((ext_vector_type(4))) __bf16 bf16x4;
typedef __attribute__((ext_vector_type(4))) float f32x4;
typedef __attribute__((ext_vector_type(16))) float f32x16;

#define MFMA16(a, b, c) __builtin_amdgcn_mfma_f32_16x16x32_bf16((a), (b), (c), 0, 0, 0)
#define MFMA32(a, b, c) __builtin_amdgcn_mfma_f32_32x32x16_bf16((a), (b), (c), 0, 0, 0)

// log2(e) / sqrt(1024)
#define QSCALE 0.045084220027780106f

__device__ __forceinline__ void glds16(const void* g, void* l) {
  __builtin_amdgcn_global_load_lds(
      (const __attribute__((address_space(1))) void*)g,
      (__attribute__((address_space(3))) void*)l, 16, 0, 0);
}

// swizzled 16B fragment read from a [rows][64] bf16 tile (128B rows, XOR-16 swizzle)
__device__ __forceinline__ bf16x8 ldsfrag(const unsigned char* base, int row, int colb) {
  return *(const bf16x8*)(base + row * 128 + (colb ^ ((row & 7) << 4)));
}

__device__ __forceinline__ uint32_t pkbf16(float a, float b) {
  uint32_t r;
  asm("v_cvt_pk_bf16_f32 %0, %1, %2" : "=v"(r) : "v"(a), "v"(b));
  return r;
}

// raw v_exp_f32: args here are far from the subnormal range, skip libm's fixup
__device__ __forceinline__ float fexp2(float x) {
#if __has_builtin(__builtin_amdgcn_exp2f)
  return __builtin_amdgcn_exp2f(x);
#else
  float r;
  asm("v_exp_f32 %0, %1" : "=v"(r) : "v"(x));
  return r;
#endif
}

__device__ __forceinline__ f32x16 zero16() {
  f32x16 v;
#pragma unroll
  for (int i = 0; i < 16; ++i) v[i] = 0.f;
  return v;
}

// ---------------- fused prep kernel: all 4 preps in one dispatch ----------------
template <int MODE>
__device__ __forceinline__ void prep_w_body(const float* __restrict__ W, bf16* __restrict__ WT,
                                            float (*tile)[256], int c0, int k0) {
  const int C = (MODE == 0) ? 3072 : 1024;
  const int lw = threadIdx.x & 63, w = threadIdx.x >> 6;
#pragma unroll
  for (int i = 0; i < 16; ++i) {
    int r = i * 4 + w;
    f32x4 v = *(const f32x4*)(W + (size_t)(k0 + r) * C + c0 + lw * 4);
    *(f32x4*)&tile[r][lw * 4] = v;
  }
  __syncthreads();
  const int c = c0 + threadIdx.x;
  int j;
  float sc = 1.0f;
  if (MODE == 0) {
    int h = c / 192, rem = c - h * 192, dd = rem / 3, wh = rem - dd * 3;
    j = wh * 1024 + h * 64 + dd;
    if (wh == 0) sc = QSCALE;
  } else {
    j = c;
  }
#pragma unroll
  for (int ch = 0; ch < 8; ++ch) {
    bf16x8 o;
#pragma unroll
    for (int i = 0; i < 8; ++i) o[i] = (bf16)(tile[ch * 8 + i][threadIdx.x] * sc);
    *(bf16x8*)(WT + (size_t)j * 1024 + k0 + ch * 8) = o;
  }
}

__global__ __launch_bounds__(256) void k_prep_all(const float* __restrict__ x,
                                                  const float* __restrict__ Wqkv,
                                                  const float* __restrict__ bqkv,
                                                  const float* __restrict__ Wproj,
                                                  bf16* __restrict__ xb, bf16* __restrict__ WQT,
                                                  bf16* __restrict__ WPT, float* __restrict__ bp) {
  __shared__ float tile[64][256];
  int bid = blockIdx.x;
  if (bid < 2048) {  // ---- x -> bf16 ----
    int gid = bid * 256 + threadIdx.x;
    const f32x4* xv = (const f32x4*)x;
    f32x4 a = xv[(size_t)gid * 2], b = xv[(size_t)gid * 2 + 1];
    bf16x8 o;
#pragma unroll
    for (int i = 0; i < 4; ++i) { o[i] = (bf16)a[i]; o[i + 4] = (bf16)b[i]; }
    *(bf16x8*)(xb + (size_t)gid * 8) = o;
    return;
  }
  bid -= 2048;
  if (bid < 192) {  // ---- Wqkv transpose+permute ----
    prep_w_body<0>(Wqkv, WQT, tile, (bid % 12) * 256, (bid / 12) * 64);
    return;
  }
  bid -= 192;
  if (bid < 64) {  // ---- Wproj transpose ----
    prep_w_body<1>(Wproj, WPT, tile, (bid % 4) * 256, (bid / 4) * 64);
    return;
  }
  bid -= 64;
  {  // ---- bias permute (12 blocks) ----
    int gid = bid * 256 + threadIdx.x;  // j in [0,3072)
    int wj = gid >> 10, rr = gid & 1023, hh = rr >> 6, d2 = rr & 63;
    float v = bqkv[hh * 192 + d2 * 3 + wj];
    bp[gid] = (wj == 0) ? v * QSCALE : v;
  }
}

// ---------------- 128x128 GEMM, K=1024: C = A[M][1024] @ BT[N][1024]^T + bias ----------------
// r15: 1D grid with XCD-chunked bijective swizzle (T1): nwg = 8*chunk, each XCD gets 4
// consecutive bm-panels x all bn -> B-panels hit its private L2 3 of 4 reads; A-panels resident.
// EPI 0: Q/K -> [b,h,n,64] bf16 (qk base, K at +4194304); V -> VT [b,h,64,n] bf16 (fused transpose)
// EPI 1: fp32 out[M][1024] + bias
template <int EPI, int NBN>
__global__ __launch_bounds__(256) void k_gemm(const bf16* __restrict__ A, const bf16* __restrict__ BT,
                                              const float* __restrict__ bias, bf16* __restrict__ qk,
                                              bf16* __restrict__ vt, float* __restrict__ outf) {
  __shared__ __align__(16) unsigned char sA[16384];
  __shared__ __align__(16) unsigned char sB[16384];
  const int tid = threadIdx.x;
  const int l = tid & 63, w = tid >> 6, g = l >> 4, l15 = l & 15;
  const int wr = w >> 1, wc = w & 1;
  // XCD-chunked swizzle: gridDim.x % 8 == 0 (768 or 256); chunk = gridDim.x / 8
  const int chunk = (EPI == 0) ? 96 : 32;
  const int wg = (blockIdx.x & 7) * chunk + (blockIdx.x >> 3);
  const int bn = wg % NBN, bm = wg / NBN;
  const unsigned char* Ab = (const unsigned char*)A + (size_t)bm * 128 * 2048;
  const unsigned char* Bb = (const unsigned char*)BT + (size_t)bn * 128 * 2048;
  f32x4 acc[4][4];
#pragma unroll
  for (int mi = 0; mi < 4; ++mi)
#pragma unroll
    for (int ni = 0; ni < 4; ++ni) acc[mi][ni] = (f32x4){0.f, 0.f, 0.f, 0.f};

  for (int kt = 0; kt < 16; ++kt) {
    const int k0b = kt * 128;  // 64 bf16 = 128 bytes per K-tile
#pragma unroll
    for (int p = 0; p < 4; ++p) {
      int co = (p * 256 + tid) * 16;
      int row = co >> 7, wb = co & 127;
      int sw = wb ^ ((row & 7) << 4);  // pre-swizzled global source, linear LDS dest
      glds16(Ab + (size_t)row * 2048 + k0b + sw, sA + co);
      glds16(Bb + (size_t)row * 2048 + k0b + sw, sB + co);
    }
    __syncthreads();
#pragma unroll
    for (int ks = 0; ks < 2; ++ks) {
      bf16x8 af[4], bfr[4];
#pragma unroll
      for (int mi = 0; mi < 4; ++mi) af[mi] = ldsfrag(sA, wr * 64 + mi * 16 + l15, ks * 64 + g * 16);
#pragma unroll
      for (int ni = 0; ni < 4; ++ni) bfr[ni] = ldsfrag(sB, wc * 64 + ni * 16 + l15, ks * 64 + g * 16);
      __builtin_amdgcn_s_setprio(1);
#pragma unroll
      for (int mi = 0; mi < 4; ++mi)
#pragma unroll
        for (int ni = 0; ni < 4; ++ni) acc[mi][ni] = MFMA16(af[mi], bfr[ni], acc[mi][ni]);
      __builtin_amdgcn_s_setprio(0);
    }
    __syncthreads();
  }
#pragma unroll
  for (int ni = 0; ni < 4; ++ni) {
    int j = bn * 128 + wc * 64 + ni * 16 + l15;
    float bj = bias[j];
#pragma unroll
    for (int mi = 0; mi < 4; ++mi) {
      int m0 = bm * 128 + wr * 64 + mi * 16 + g * 4;  // C/D: row=(l>>4)*4+reg, col=l&15
      float v[4];
#pragma unroll
      for (int rr = 0; rr < 4; ++rr) v[rr] = acc[mi][ni][rr] + bj;
      if (EPI == 0) {
        int which = j >> 10, r = j & 1023, h = r >> 6, dd = r & 63;
        int b = m0 >> 11, nn = m0 & 2047;
        if (which < 2) {
#pragma unroll
          for (int rr = 0; rr < 4; ++rr)
            qk[(size_t)which * 4194304 + (((size_t)b * 16 + h) * 2048 + nn + rr) * 64 + dd] = (bf16)v[rr];
        } else {
          bf16x4 pw = {(bf16)v[0], (bf16)v[1], (bf16)v[2], (bf16)v[3]};
          *(bf16x4*)(vt + (((size_t)b * 16 + h) * 64 + dd) * 2048 + nn) = pw;
        }
      } else {
#pragma unroll
        for (int rr = 0; rr < 4; ++rr) outf[(size_t)(m0 + rr) * 1024 + j] = v[rr];
      }
    }
  }
}

// ---------------- flash attention: 32x32 MFMA, 64 q/wave, in-register P, KV-split 2 groups --------
// Frozen at the r9/r14 structure (best proven: ~51us, VGPR 116, no spill; r11/r12/r13
// restructures all spill-blocked at the 128-VGPR wall). absmax canary: exactly 9.766e-4.
__global__ __launch_bounds__(512, 1) void k_attn(const bf16* __restrict__ Qg, const bf16* __restrict__ Kg,
                                                 const bf16* __restrict__ VTg, bf16* __restrict__ Og) {
  // [0,32768): K tiles [grp][buf][8192]      (epilogue: mbuf low half)
  // [32768,65536): V tiles [grp][buf][8192]  (epilogue: mbuf high half; sO after 2nd barrier)
  // [65536,67584): lsum merge buf [8][64] f32
  __shared__ __align__(16) unsigned char smem[67584];
  const int tid = threadIdx.x;
  const int l = tid & 63, w = tid >> 6;
  const int q = l & 31, hi = l >> 5;
  const int g = w >> 2, wl = w & 3;
  const int stid = tid & 255;

  const int bid = blockIdx.x;                  // 256 blocks
  const int wg = (bid & 7) * 32 + (bid >> 3);  // XCD-chunked: 4 consecutive bh per XCD
  const int bh = wg >> 3;
  const int q0w = (wg & 7) * 256 + wl * 64;    // this wave's 64 q-rows

  // Q B-fragments (Q pre-scaled by log2e/32): qf[qt][ks] = Q[q0w+qt*32+q][ks*16 + hi*8 + j]
  bf16x8 qf[2][4];
#pragma unroll
  for (int qt = 0; qt < 2; ++qt)
#pragma unroll
    for (int ks = 0; ks < 4; ++ks)
      qf[qt][ks] = *(const bf16x8*)(Qg + ((size_t)bh * 2048 + q0w + qt * 32 + q) * 64 + ks * 16 + hi * 8);

  f32x16 oacc[2][2];  // [qt][dt] O^T[dd][q]: col q = l&31, row dd = dt*32 + (reg&3)+8*(reg>>2)+4*hi
#pragma unroll
  for (int qt = 0; qt < 2; ++qt) { oacc[qt][0] = zero16(); oacc[qt][1] = zero16(); }
  float lrun4[2][4] = {{0.f, 0.f, 0.f, 0.f}, {0.f, 0.f, 0.f, 0.f}};
  bf16x8 pb[2][4];  // packed P of the pending tile, per qt

  const unsigned char* Kb = (const unsigned char*)Kg + (size_t)bh * 262144 + (size_t)g * 131072;
  const unsigned char* Vb = (const unsigned char*)VTg + (size_t)bh * 262144 + (size_t)g * 2048;
  unsigned char* sKg = smem + g * 16384;
  unsigned char* sVg = smem + 32768 + g * 16384;

  // per-thread staging coords (loop-invariant)
  const int co0 = stid * 16, co1 = (256 + stid) * 16;
  const int row0 = co0 >> 7, row1 = co1 >> 7;
  const int sw0 = (co0 & 127) ^ ((row0 & 7) << 4), sw1 = (co1 & 127) ^ ((row1 & 7) << 4);

#define STAGE_K(kb_, buf_)                                                        \
  do {                                                                            \
    const unsigned char* Ksrc = Kb + (size_t)(kb_) * 8192;                        \
    glds16(Ksrc + (co0 & ~127) + sw0, sKg + (buf_) * 8192 + co0);                 \
    glds16(Ksrc + (co1 & ~127) + sw1, sKg + (buf_) * 8192 + co1);                 \
  } while (0)
#define STAGE_V(kb_, buf_)                                                        \
  do {                                                                            \
    glds16(Vb + (size_t)row0 * 4096 + (size_t)(kb_) * 128 + sw0, sVg + (buf_) * 8192 + co0); \
    glds16(Vb + (size_t)row1 * 4096 + (size_t)(kb_) * 128 + sw1, sVg + (buf_) * 8192 + co1); \
  } while (0)

  // QK^T + exp + pack for one 64-key tile, both qt subtiles sharing the K fragments
#define QK_EXP_PACK(kbase_)                                                       \
  do {                                                                            \
    _Pragma("unroll") for (int kt = 0; kt < 2; ++kt) {                            \
      bf16x8 kf[4];                                                               \
      _Pragma("unroll") for (int ks = 0; ks < 4; ++ks)                            \
        kf[ks] = ldsfrag((kbase_), kt * 32 + q, ks * 32 + hi * 16);               \
      _Pragma("unroll") for (int qt = 0; qt < 2; ++qt) {                          \
        f32x16 sacc = zero16();                                                   \
        __builtin_amdgcn_s_setprio(1);                                            \
        _Pragma("unroll") for (int ks = 0; ks < 4; ++ks)                          \
          sacc = MFMA32(kf[ks], qf[qt][ks], sacc);                                \
        __builtin_amdgcn_s_setprio(0);                                            \
        float pe[16];                                                             \
        _Pragma("unroll") for (int r = 0; r < 16; ++r) pe[r] = fexp2(sacc[r]);    \
        _Pragma("unroll") for (int m = 0; m < 4; ++m)                             \
          _Pragma("unroll") for (int j = 0; j < 4; ++j) lrun4[qt][j] += pe[4 * m + j]; \
        uint32_t c[4][2];                                                         \
        _Pragma("unroll") for (int m = 0; m < 4; ++m) {                           \
          c[m][0] = pkbf16(pe[4 * m], pe[4 * m + 1]);                             \
          c[m][1] = pkbf16(pe[4 * m + 2], pe[4 * m + 3]);                         \
        }                                                                         \
        _Pragma("unroll") for (int s = 0; s < 2; ++s) {                           \
          uint32_t x0 = c[2 * s][0], y0 = c[2 * s + 1][0];                        \
          uint32_t x1 = c[2 * s][1], y1 = c[2 * s + 1][1];                        \
          asm("v_permlane32_swap_b32 %0, %1" : "+v"(x0), "+v"(y0));               \
          asm("v_permlane32_swap_b32 %0, %1" : "+v"(x1), "+v"(y1));               \
          union { uint32_t u[4]; bf16x8 v; } bfr;                                 \
          bfr.u[0] = x0; bfr.u[1] = x1; bfr.u[2] = y0; bfr.u[3] = y1;             \
          pb[qt][kt * 2 + s] = bfr.v;                                             \
        }                                                                         \
      }                                                                           \
    }                                                                             \
  } while (0)

  // PV: both qt share each V fragment (ks order 0..3 per [qt][dt])
#define PV_TILE(vbase_)                                                           \
  do {                                                                            \
    __builtin_amdgcn_s_setprio(1);                                                \
    _Pragma("unroll") for (int ks = 0; ks < 4; ++ks)                              \
      _Pragma("unroll") for (int dt = 0; dt < 2; ++dt) {                          \
        bf16x8 vf = ldsfrag((vbase_), dt * 32 + q, ks * 32 + hi * 16);            \
        _Pragma("unroll") for (int qtp = 0; qtp < 2; ++qtp)                       \
          oacc[qtp][dt] = MFMA32(vf, pb[qtp][ks], oacc[qtp][dt]);                 \
      }                                                                           \
    __builtin_amdgcn_s_setprio(0);                                                \
  } while (0)

  // ---- prologue: land K0+V0, compute P(0), land K1 ----
  STAGE_K(0, 0);
  STAGE_V(0, 0);
  __syncthreads();
  STAGE_K(1, 1);
  QK_EXP_PACK(sKg);  // tile 0 from K buf 0
  __syncthreads();   // K1 landed
  int cur = 0;

  // ---- steady state: PV(kb) || QK(kb+1), one barrier per tile ----
  for (int kb = 0; kb < 15; ++kb) {
    const int nxt = cur ^ 1;
    if (kb < 14) STAGE_K(kb + 2, cur);  // K(kb) buffer free (read finished last iter)
    STAGE_V(kb + 1, nxt);               // V(kb) in cur being read this iter
    PV_TILE(sVg + cur * 8192);          // consumes pb = P(kb)
    QK_EXP_PACK(sKg + nxt * 8192);      // produces pb = P(kb+1)
    __syncthreads();                    // drains stages; all waves done with cur-buffers
    cur = nxt;
  }
  PV_TILE(sVg + cur * 8192);  // tile 15

#undef STAGE_K
#undef STAGE_V
#undef QK_EXP_PACK
#undef PV_TILE

  float lrun[2];
#pragma unroll
  for (int qt = 0; qt < 2; ++qt)
    lrun[qt] = (lrun4[qt][0] + lrun4[qt][1]) + (lrun4[qt][2] + lrun4[qt][3]);

  // ---- merge the two KV halves (additive: no-max softmax), then transpose O^T and store ----
  float* mbuf = (float*)smem;          // [4 waves][2 qt][32 regs][64 lanes] f32 = 64KB over K+V tiles
  float* lb = (float*)(smem + 65536);  // [4 waves][2 qt][64]
  if (g == 1) {
#pragma unroll
    for (int qt = 0; qt < 2; ++qt) {
#pragma unroll
      for (int dt = 0; dt < 2; ++dt)
#pragma unroll
        for (int r = 0; r < 16; ++r)
          mbuf[((wl * 64 + qt * 32 + dt * 16 + r) << 6) + l] = oacc[qt][dt][r];
      lb[(wl * 2 + qt) * 64 + l] = lrun[qt];
    }
  }
  __syncthreads();
  if (g == 0) {
#pragma unroll
    for (int qt = 0; qt < 2; ++qt)
#pragma unroll
      for (int dt = 0; dt < 2; ++dt)
#pragma unroll
        for (int r = 0; r < 16; ++r)
          oacc[qt][dt][r] += mbuf[((wl * 64 + qt * 32 + dt * 16 + r) << 6) + l];
  }
  __syncthreads();  // all mbuf reads done before sO (32768..49152) overwrites that region
  if (g == 0) {
    const int b = bh >> 4, h = bh & 15;
    unsigned char* sO = smem + 32768 + wl * 4096;  // per-wave [32 q][64 dd] bf16, XOR-16 swizzled
#pragma unroll
    for (int qt = 0; qt < 2; ++qt) {
      float lr = lrun[qt] + lb[(wl * 2 + qt) * 64 + l];
      float ps = lr + __shfl_xor(lr, 32);
      float linv = 1.0f / ps;
#pragma unroll
      for (int dt = 0; dt < 2; ++dt)
#pragma unroll
        for (int m = 0; m < 4; ++m) {
          uint32_t b0 = pkbf16(oacc[qt][dt][4 * m] * linv, oacc[qt][dt][4 * m + 1] * linv);
          uint32_t b1 = pkbf16(oacc[qt][dt][4 * m + 2] * linv, oacc[qt][dt][4 * m + 3] * linv);
          int byteo = (dt * 64 + m * 16 + hi * 8) ^ ((q & 7) << 4);
          uint32_t* dst = (uint32_t*)(sO + q * 128 + byteo);
          dst[0] = b0; dst[1] = b1;
        }
      const int q0 = q0w + qt * 32;
#pragma unroll
      for (int rd = 0; rd < 4; ++rd) {
        int byteo = hi * 64 + rd * 16;
        bf16x8 v = *(const bf16x8*)(sO + q * 128 + (byteo ^ ((q & 7) << 4)));
        *(bf16x8*)(Og + ((size_t)b * 2048 + q0 + q) * 1024 + h * 64 + byteo / 2) = v;
      }
    }
  }
}

extern "C" void kernel_launch(void* const* d_in, const int* in_sizes, int n_in,
                              void* d_out, int out_size, void* d_ws, size_t ws_size,
                              hipStream_t stream) {
  const float* x = (const float*)d_in[0];
  const float* Wqkv = (const float*)d_in[1];
  const float* bqkv = (const float*)d_in[2];
  const float* Wproj = (const float*)d_in[3];
  const float* bproj = (const float*)d_in[4];
  float* out = (float*)d_out;
  char* ws = (char*)d_ws;

  bf16* XB = (bf16*)(ws + 0);            // 8 MB x_bf16 [4096][1024]; reused as attn-out
  bf16* WQT = (bf16*)(ws + 8388608);     // 6 MB WqkvT (permuted, Q pre-scaled) [3072][1024]
  float* BQP = (float*)(ws + 14680064);  // 16 KB permuted bias (Q part pre-scaled)
  bf16* WPT = (bf16*)(ws + 14696448);    // 2 MB WprojT [1024][1024]
  bf16* Q = (bf16*)(ws + 16793600);      // 8 MB [2][16][2048][64]
  bf16* K = (bf16*)(ws + 25182208);      // 8 MB (contiguous after Q: qk base + 4194304 elems)
  bf16* VT = (bf16*)(ws + 33570816);     // 8 MB [2][16][64][2048] (written directly by gemm<0>)
  bf16* AO = XB;
  (void)K;
  (void)ws_size;

  k_prep_all<<<2316, 256, 0, stream>>>(x, Wqkv, bqkv, Wproj, XB, WQT, WPT, BQP);
  k_gemm<0, 24><<<768, 256, 0, stream>>>(XB, WQT, BQP, Q, VT, nullptr);
  k_attn<<<256, 512, 0, stream>>>(Q, Q + 4194304, VT, AO);
  k_gemm<1, 8><<<256, 256, 0, stream>>>(AO, WPT, bproj, nullptr, nullptr, out);
}

// Round 16
// 110.346 us; speedup vs baseline: 1.2664x; 1.0352x over previous
//
#include <hip/hip_runtime.h>
#include <hip/hip_bf16.h>
#include <stdint.h>

typedef __bf16 bf16;
typedef __attribute__((ext_vector_type(8))) __bf16 bf16x8;
typedef __attribute__((ext_vector_type(4))) __bf16 bf16x4;
typedef __attribute__((ext_vector_type(4))) float f32x4;
typedef __attribute__((ext_vector_type(16))) float f32x16;

#define MFMA16(a, b, c) __builtin_amdgcn_mfma_f32_16x16x32_bf16((a), (b), (c), 0, 0, 0)
#define MFMA32(a, b, c) __builtin_amdgcn_mfma_f32_32x32x16_bf16((a), (b), (c), 0, 0, 0)

// log2(e) / sqrt(1024)
#define QSCALE 0.045084220027780106f

__device__ __forceinline__ void glds16(const void* g, void* l) {
  __builtin_amdgcn_global_load_lds(
      (const __attribute__((address_space(1))) void*)g,
      (__attribute__((address_space(3))) void*)l, 16, 0, 0);
}

// swizzled 16B fragment read from a [rows][64] bf16 tile (128B rows, XOR-16 swizzle)
__device__ __forceinline__ bf16x8 ldsfrag(const unsigned char* base, int row, int colb) {
  return *(const bf16x8*)(base + row * 128 + (colb ^ ((row & 7) << 4)));
}

__device__ __forceinline__ uint32_t pkbf16(float a, float b) {
  uint32_t r;
  asm("v_cvt_pk_bf16_f32 %0, %1, %2" : "=v"(r) : "v"(a), "v"(b));
  return r;
}

// raw v_exp_f32: args here are far from the subnormal range, skip libm's fixup
__device__ __forceinline__ float fexp2(float x) {
#if __has_builtin(__builtin_amdgcn_exp2f)
  return __builtin_amdgcn_exp2f(x);
#else
  float r;
  asm("v_exp_f32 %0, %1" : "=v"(r) : "v"(x));
  return r;
#endif
}

__device__ __forceinline__ f32x16 zero16() {
  f32x16 v;
#pragma unroll
  for (int i = 0; i < 16; ++i) v[i] = 0.f;
  return v;
}

// ---------------- fused prep kernel: all 4 preps in one dispatch ----------------
template <int MODE>
__device__ __forceinline__ void prep_w_body(const float* __restrict__ W, bf16* __restrict__ WT,
                                            float (*tile)[256], int c0, int k0) {
  const int C = (MODE == 0) ? 3072 : 1024;
  const int lw = threadIdx.x & 63, w = threadIdx.x >> 6;
#pragma unroll
  for (int i = 0; i < 16; ++i) {
    int r = i * 4 + w;
    f32x4 v = *(const f32x4*)(W + (size_t)(k0 + r) * C + c0 + lw * 4);
    *(f32x4*)&tile[r][lw * 4] = v;
  }
  __syncthreads();
  const int c = c0 + threadIdx.x;
  int j;
  float sc = 1.0f;
  if (MODE == 0) {
    int h = c / 192, rem = c - h * 192, dd = rem / 3, wh = rem - dd * 3;
    j = wh * 1024 + h * 64 + dd;
    if (wh == 0) sc = QSCALE;
  } else {
    j = c;
  }
#pragma unroll
  for (int ch = 0; ch < 8; ++ch) {
    bf16x8 o;
#pragma unroll
    for (int i = 0; i < 8; ++i) o[i] = (bf16)(tile[ch * 8 + i][threadIdx.x] * sc);
    *(bf16x8*)(WT + (size_t)j * 1024 + k0 + ch * 8) = o;
  }
}

__global__ __launch_bounds__(256) void k_prep_all(const float* __restrict__ x,
                                                  const float* __restrict__ Wqkv,
                                                  const float* __restrict__ bqkv,
                                                  const float* __restrict__ Wproj,
                                                  bf16* __restrict__ xb, bf16* __restrict__ WQT,
                                                  bf16* __restrict__ WPT, float* __restrict__ bp) {
  __shared__ float tile[64][256];
  int bid = blockIdx.x;
  if (bid < 2048) {  // ---- x -> bf16 ----
    int gid = bid * 256 + threadIdx.x;
    const f32x4* xv = (const f32x4*)x;
    f32x4 a = xv[(size_t)gid * 2], b = xv[(size_t)gid * 2 + 1];
    bf16x8 o;
#pragma unroll
    for (int i = 0; i < 4; ++i) { o[i] = (bf16)a[i]; o[i + 4] = (bf16)b[i]; }
    *(bf16x8*)(xb + (size_t)gid * 8) = o;
    return;
  }
  bid -= 2048;
  if (bid < 192) {  // ---- Wqkv transpose+permute ----
    prep_w_body<0>(Wqkv, WQT, tile, (bid % 12) * 256, (bid / 12) * 64);
    return;
  }
  bid -= 192;
  if (bid < 64) {  // ---- Wproj transpose ----
    prep_w_body<1>(Wproj, WPT, tile, (bid % 4) * 256, (bid / 4) * 64);
    return;
  }
  bid -= 64;
  {  // ---- bias permute (12 blocks) ----
    int gid = bid * 256 + threadIdx.x;  // j in [0,3072)
    int wj = gid >> 10, rr = gid & 1023, hh = rr >> 6, d2 = rr & 63;
    float v = bqkv[hh * 192 + d2 * 3 + wj];
    bp[gid] = (wj == 0) ? v * QSCALE : v;
  }
}

// ---------------- 128x128 GEMM (QKV), K=1024, XCD-chunked swizzle ----------------
// EPI 0 only now: Q/K -> [b,h,n,64] bf16 (qk base, K at +4194304); V -> VT (fused transpose)
__global__ __launch_bounds__(256) void k_gemm_qkv(const bf16* __restrict__ A, const bf16* __restrict__ BT,
                                                  const float* __restrict__ bias, bf16* __restrict__ qk,
                                                  bf16* __restrict__ vt) {
  __shared__ __align__(16) unsigned char sA[16384];
  __shared__ __align__(16) unsigned char sB[16384];
  const int tid = threadIdx.x;
  const int l = tid & 63, w = tid >> 6, g = l >> 4, l15 = l & 15;
  const int wr = w >> 1, wc = w & 1;
  // XCD-chunked swizzle: 768 blocks = 8 x 96
  const int wg = (blockIdx.x & 7) * 96 + (blockIdx.x >> 3);
  const int bn = wg % 24, bm = wg / 24;
  const unsigned char* Ab = (const unsigned char*)A + (size_t)bm * 128 * 2048;
  const unsigned char* Bb = (const unsigned char*)BT + (size_t)bn * 128 * 2048;
  f32x4 acc[4][4];
#pragma unroll
  for (int mi = 0; mi < 4; ++mi)
#pragma unroll
    for (int ni = 0; ni < 4; ++ni) acc[mi][ni] = (f32x4){0.f, 0.f, 0.f, 0.f};

  for (int kt = 0; kt < 16; ++kt) {
    const int k0b = kt * 128;  // 64 bf16 = 128 bytes per K-tile
#pragma unroll
    for (int p = 0; p < 4; ++p) {
      int co = (p * 256 + tid) * 16;
      int row = co >> 7, wb = co & 127;
      int sw = wb ^ ((row & 7) << 4);  // pre-swizzled global source, linear LDS dest
      glds16(Ab + (size_t)row * 2048 + k0b + sw, sA + co);
      glds16(Bb + (size_t)row * 2048 + k0b + sw, sB + co);
    }
    __syncthreads();
#pragma unroll
    for (int ks = 0; ks < 2; ++ks) {
      bf16x8 af[4], bfr[4];
#pragma unroll
      for (int mi = 0; mi < 4; ++mi) af[mi] = ldsfrag(sA, wr * 64 + mi * 16 + l15, ks * 64 + g * 16);
#pragma unroll
      for (int ni = 0; ni < 4; ++ni) bfr[ni] = ldsfrag(sB, wc * 64 + ni * 16 + l15, ks * 64 + g * 16);
      __builtin_amdgcn_s_setprio(1);
#pragma unroll
      for (int mi = 0; mi < 4; ++mi)
#pragma unroll
        for (int ni = 0; ni < 4; ++ni) acc[mi][ni] = MFMA16(af[mi], bfr[ni], acc[mi][ni]);
      __builtin_amdgcn_s_setprio(0);
    }
    __syncthreads();
  }
#pragma unroll
  for (int ni = 0; ni < 4; ++ni) {
    int j = bn * 128 + wc * 64 + ni * 16 + l15;
    float bj = bias[j];
#pragma unroll
    for (int mi = 0; mi < 4; ++mi) {
      int m0 = bm * 128 + wr * 64 + mi * 16 + g * 4;  // C/D: row=(l>>4)*4+reg, col=l&15
      float v[4];
#pragma unroll
      for (int rr = 0; rr < 4; ++rr) v[rr] = acc[mi][ni][rr] + bj;
      int which = j >> 10, r = j & 1023, h = r >> 6, dd = r & 63;
      int b = m0 >> 11, nn = m0 & 2047;
      if (which < 2) {
#pragma unroll
        for (int rr = 0; rr < 4; ++rr)
          qk[(size_t)which * 4194304 + (((size_t)b * 16 + h) * 2048 + nn + rr) * 64 + dd] = (bf16)v[rr];
      } else {
        bf16x4 pw = {(bf16)v[0], (bf16)v[1], (bf16)v[2], (bf16)v[3]};
        *(bf16x4*)(vt + (((size_t)b * 16 + h) * 64 + dd) * 2048 + nn) = pw;
      }
    }
  }
}

// ---------------- 64x128 proj GEMM (r16): occupancy fix for the 8.6 GF proj ----------------
// Old 128x128 grid = 256 blocks = 1 block/CU = 1 wave/SIMD (starved). New: 64x128 tile,
// 512 blocks = 2 blocks/CU = 8 waves/CU, two independent barrier domains. Per-wave 64x32
// output (acc 32 VGPR). Same per-element K-chain (kt 0..15, ks 0..1, MFMA16) as before ->
// bit-exact output. XCD-chunked: 512 = 8 x 64; B (2 MB) L2-resident per XCD.
__global__ __launch_bounds__(256) void k_gemm_proj(const bf16* __restrict__ A, const bf16* __restrict__ BT,
                                                   const float* __restrict__ bias, float* __restrict__ outf) {
  __shared__ __align__(16) unsigned char sA[8192];   // [64][64] bf16, swizzled 128B rows
  __shared__ __align__(16) unsigned char sB[16384];  // [128][64]
  const int tid = threadIdx.x;
  const int l = tid & 63, w = tid >> 6, g = l >> 4, l15 = l & 15;
  const int wg = (blockIdx.x & 7) * 64 + (blockIdx.x >> 3);
  const int bn = wg & 7, bm = wg >> 3;
  const unsigned char* Ab = (const unsigned char*)A + (size_t)bm * 64 * 2048;
  const unsigned char* Bb = (const unsigned char*)BT + (size_t)bn * 128 * 2048;
  f32x4 acc[4][2];
#pragma unroll
  for (int mi = 0; mi < 4; ++mi)
#pragma unroll
    for (int ni = 0; ni < 2; ++ni) acc[mi][ni] = (f32x4){0.f, 0.f, 0.f, 0.f};

  for (int kt = 0; kt < 16; ++kt) {
    const int k0b = kt * 128;
#pragma unroll
    for (int p = 0; p < 2; ++p) {  // A: 8KB = 2 x 16B/thread
      int co = (p * 256 + tid) * 16;
      int row = co >> 7;
      int sw = (co & 127) ^ ((row & 7) << 4);
      glds16(Ab + (size_t)row * 2048 + k0b + sw, sA + co);
    }
#pragma unroll
    for (int p = 0; p < 4; ++p) {  // B: 16KB = 4 x 16B/thread
      int co = (p * 256 + tid) * 16;
      int row = co >> 7;
      int sw = (co & 127) ^ ((row & 7) << 4);
      glds16(Bb + (size_t)row * 2048 + k0b + sw, sB + co);
    }
    __syncthreads();
#pragma unroll
    for (int ks = 0; ks < 2; ++ks) {
      bf16x8 af[4], bfr[2];
#pragma unroll
      for (int mi = 0; mi < 4; ++mi) af[mi] = ldsfrag(sA, mi * 16 + l15, ks * 64 + g * 16);
#pragma unroll
      for (int ni = 0; ni < 2; ++ni) bfr[ni] = ldsfrag(sB, w * 32 + ni * 16 + l15, ks * 64 + g * 16);
      __builtin_amdgcn_s_setprio(1);
#pragma unroll
      for (int mi = 0; mi < 4; ++mi)
#pragma unroll
        for (int ni = 0; ni < 2; ++ni) acc[mi][ni] = MFMA16(af[mi], bfr[ni], acc[mi][ni]);
      __builtin_amdgcn_s_setprio(0);
    }
    __syncthreads();
  }
#pragma unroll
  for (int ni = 0; ni < 2; ++ni) {
    int j = bn * 128 + w * 32 + ni * 16 + l15;
    float bj = bias[j];
#pragma unroll
    for (int mi = 0; mi < 4; ++mi) {
      int m0 = bm * 64 + mi * 16 + g * 4;
#pragma unroll
      for (int rr = 0; rr < 4; ++rr) outf[(size_t)(m0 + rr) * 1024 + j] = acc[mi][ni][rr] + bj;
    }
  }
}

// ---------------- flash attention: 32x32 MFMA, 64 q/wave, in-register P, KV-split 2 groups --------
// Frozen at the r9/r14 structure (best proven: ~51us, VGPR 116, no spill). absmax canary: 9.766e-4.
__global__ __launch_bounds__(512, 1) void k_attn(const bf16* __restrict__ Qg, const bf16* __restrict__ Kg,
                                                 const bf16* __restrict__ VTg, bf16* __restrict__ Og) {
  // [0,32768): K tiles [grp][buf][8192]      (epilogue: mbuf low half)
  // [32768,65536): V tiles [grp][buf][8192]  (epilogue: mbuf high half; sO after 2nd barrier)
  // [65536,67584): lsum merge buf [8][64] f32
  __shared__ __align__(16) unsigned char smem[67584];
  const int tid = threadIdx.x;
  const int l = tid & 63, w = tid >> 6;
  const int q = l & 31, hi = l >> 5;
  const int g = w >> 2, wl = w & 3;
  const int stid = tid & 255;

  const int bid = blockIdx.x;                  // 256 blocks
  const int wg = (bid & 7) * 32 + (bid >> 3);  // XCD-chunked: 4 consecutive bh per XCD
  const int bh = wg >> 3;
  const int q0w = (wg & 7) * 256 + wl * 64;    // this wave's 64 q-rows

  // Q B-fragments (Q pre-scaled by log2e/32): qf[qt][ks] = Q[q0w+qt*32+q][ks*16 + hi*8 + j]
  bf16x8 qf[2][4];
#pragma unroll
  for (int qt = 0; qt < 2; ++qt)
#pragma unroll
    for (int ks = 0; ks < 4; ++ks)
      qf[qt][ks] = *(const bf16x8*)(Qg + ((size_t)bh * 2048 + q0w + qt * 32 + q) * 64 + ks * 16 + hi * 8);

  f32x16 oacc[2][2];  // [qt][dt] O^T[dd][q]: col q = l&31, row dd = dt*32 + (reg&3)+8*(reg>>2)+4*hi
#pragma unroll
  for (int qt = 0; qt < 2; ++qt) { oacc[qt][0] = zero16(); oacc[qt][1] = zero16(); }
  float lrun4[2][4] = {{0.f, 0.f, 0.f, 0.f}, {0.f, 0.f, 0.f, 0.f}};
  bf16x8 pb[2][4];  // packed P of the pending tile, per qt

  const unsigned char* Kb = (const unsigned char*)Kg + (size_t)bh * 262144 + (size_t)g * 131072;
  const unsigned char* Vb = (const unsigned char*)VTg + (size_t)bh * 262144 + (size_t)g * 2048;
  unsigned char* sKg = smem + g * 16384;
  unsigned char* sVg = smem + 32768 + g * 16384;

  // per-thread staging coords (loop-invariant)
  const int co0 = stid * 16, co1 = (256 + stid) * 16;
  const int row0 = co0 >> 7, row1 = co1 >> 7;
  const int sw0 = (co0 & 127) ^ ((row0 & 7) << 4), sw1 = (co1 & 127) ^ ((row1 & 7) << 4);

#define STAGE_K(kb_, buf_)                                                        \
  do {                                                                            \
    const unsigned char* Ksrc = Kb + (size_t)(kb_) * 8192;                        \
    glds16(Ksrc + (co0 & ~127) + sw0, sKg + (buf_) * 8192 + co0);                 \
    glds16(Ksrc + (co1 & ~127) + sw1, sKg + (buf_) * 8192 + co1);                 \
  } while (0)
#define STAGE_V(kb_, buf_)                                                        \
  do {                                                                            \
    glds16(Vb + (size_t)row0 * 4096 + (size_t)(kb_) * 128 + sw0, sVg + (buf_) * 8192 + co0); \
    glds16(Vb + (size_t)row1 * 4096 + (size_t)(kb_) * 128 + sw1, sVg + (buf_) * 8192 + co1); \
  } while (0)

  // QK^T + exp + pack for one 64-key tile, both qt subtiles sharing the K fragments
#define QK_EXP_PACK(kbase_)                                                       \
  do {                                                                            \
    _Pragma("unroll") for (int kt = 0; kt < 2; ++kt) {                            \
      bf16x8 kf[4];                                                               \
      _Pragma("unroll") for (int ks = 0; ks < 4; ++ks)                            \
        kf[ks] = ldsfrag((kbase_), kt * 32 + q, ks * 32 + hi * 16);               \
      _Pragma("unroll") for (int qt = 0; qt < 2; ++qt) {                          \
        f32x16 sacc = zero16();                                                   \
        __builtin_amdgcn_s_setprio(1);                                            \
        _Pragma("unroll") for (int ks = 0; ks < 4; ++ks)                          \
          sacc = MFMA32(kf[ks], qf[qt][ks], sacc);                                \
        __builtin_amdgcn_s_setprio(0);                                            \
        float pe[16];                                                             \
        _Pragma("unroll") for (int r = 0; r < 16; ++r) pe[r] = fexp2(sacc[r]);    \
        _Pragma("unroll") for (int m = 0; m < 4; ++m)                             \
          _Pragma("unroll") for (int j = 0; j < 4; ++j) lrun4[qt][j] += pe[4 * m + j]; \
        uint32_t c[4][2];                                                         \
        _Pragma("unroll") for (int m = 0; m < 4; ++m) {                           \
          c[m][0] = pkbf16(pe[4 * m], pe[4 * m + 1]);                             \
          c[m][1] = pkbf16(pe[4 * m + 2], pe[4 * m + 3]);                         \
        }                                                                         \
        _Pragma("unroll") for (int s = 0; s < 2; ++s) {                           \
          uint32_t x0 = c[2 * s][0], y0 = c[2 * s + 1][0];                        \
          uint32_t x1 = c[2 * s][1], y1 = c[2 * s + 1][1];                        \
          asm("v_permlane32_swap_b32 %0, %1" : "+v"(x0), "+v"(y0));               \
          asm("v_permlane32_swap_b32 %0, %1" : "+v"(x1), "+v"(y1));               \
          union { uint32_t u[4]; bf16x8 v; } bfr;                                 \
          bfr.u[0] = x0; bfr.u[1] = x1; bfr.u[2] = y0; bfr.u[3] = y1;             \
          pb[qt][kt * 2 + s] = bfr.v;                                             \
        }                                                                         \
      }                                                                           \
    }                                                                             \
  } while (0)

  // PV: both qt share each V fragment (ks order 0..3 per [qt][dt])
#define PV_TILE(vbase_)                                                           \
  do {                                                                            \
    __builtin_amdgcn_s_setprio(1);                                                \
    _Pragma("unroll") for (int ks = 0; ks < 4; ++ks)                              \
      _Pragma("unroll") for (int dt = 0; dt < 2; ++dt) {                          \
        bf16x8 vf = ldsfrag((vbase_), dt * 32 + q, ks * 32 + hi * 16);            \
        _Pragma("unroll") for (int qtp = 0; qtp < 2; ++qtp)                       \
          oacc[qtp][dt] = MFMA32(vf, pb[qtp][ks], oacc[qtp][dt]);                 \
      }                                                                           \
    __builtin_amdgcn_s_setprio(0);                                                \
  } while (0)

  // ---- prologue: land K0+V0, compute P(0), land K1 ----
  STAGE_K(0, 0);
  STAGE_V(0, 0);
  __syncthreads();
  STAGE_K(1, 1);
  QK_EXP_PACK(sKg);  // tile 0 from K buf 0
  __syncthreads();   // K1 landed
  int cur = 0;

  // ---- steady state: PV(kb) || QK(kb+1), one barrier per tile ----
  for (int kb = 0; kb < 15; ++kb) {
    const int nxt = cur ^ 1;
    if (kb < 14) STAGE_K(kb + 2, cur);  // K(kb) buffer free (read finished last iter)
    STAGE_V(kb + 1, nxt);               // V(kb) in cur being read this iter
    PV_TILE(sVg + cur * 8192);          // consumes pb = P(kb)
    QK_EXP_PACK(sKg + nxt * 8192);      // produces pb = P(kb+1)
    __syncthreads();                    // drains stages; all waves done with cur-buffers
    cur = nxt;
  }
  PV_TILE(sVg + cur * 8192);  // tile 15

#undef STAGE_K
#undef STAGE_V
#undef QK_EXP_PACK
#undef PV_TILE

  float lrun[2];
#pragma unroll
  for (int qt = 0; qt < 2; ++qt)
    lrun[qt] = (lrun4[qt][0] + lrun4[qt][1]) + (lrun4[qt][2] + lrun4[qt][3]);

  // ---- merge the two KV halves (additive: no-max softmax), then transpose O^T and store ----
  float* mbuf = (float*)smem;          // [4 waves][2 qt][32 regs][64 lanes] f32 = 64KB over K+V tiles
  float* lb = (float*)(smem + 65536);  // [4 waves][2 qt][64]
  if (g == 1) {
#pragma unroll
    for (int qt = 0; qt < 2; ++qt) {
#pragma unroll
      for (int dt = 0; dt < 2; ++dt)
#pragma unroll
        for (int r = 0; r < 16; ++r)
          mbuf[((wl * 64 + qt * 32 + dt * 16 + r) << 6) + l] = oacc[qt][dt][r];
      lb[(wl * 2 + qt) * 64 + l] = lrun[qt];
    }
  }
  __syncthreads();
  if (g == 0) {
#pragma unroll
    for (int qt = 0; qt < 2; ++qt)
#pragma unroll
      for (int dt = 0; dt < 2; ++dt)
#pragma unroll
        for (int r = 0; r < 16; ++r)
          oacc[qt][dt][r] += mbuf[((wl * 64 + qt * 32 + dt * 16 + r) << 6) + l];
  }
  __syncthreads();  // all mbuf reads done before sO (32768..49152) overwrites that region
  if (g == 0) {
    const int b = bh >> 4, h = bh & 15;
    unsigned char* sO = smem + 32768 + wl * 4096;  // per-wave [32 q][64 dd] bf16, XOR-16 swizzled
#pragma unroll
    for (int qt = 0; qt < 2; ++qt) {
      float lr = lrun[qt] + lb[(wl * 2 + qt) * 64 + l];
      float ps = lr + __shfl_xor(lr, 32);
      float linv = 1.0f / ps;
#pragma unroll
      for (int dt = 0; dt < 2; ++dt)
#pragma unroll
        for (int m = 0; m < 4; ++m) {
          uint32_t b0 = pkbf16(oacc[qt][dt][4 * m] * linv, oacc[qt][dt][4 * m + 1] * linv);
          uint32_t b1 = pkbf16(oacc[qt][dt][4 * m + 2] * linv, oacc[qt][dt][4 * m + 3] * linv);
          int byteo = (dt * 64 + m * 16 + hi * 8) ^ ((q & 7) << 4);
          uint32_t* dst = (uint32_t*)(sO + q * 128 + byteo);
          dst[0] = b0; dst[1] = b1;
        }
      const int q0 = q0w + qt * 32;
#pragma unroll
      for (int rd = 0; rd < 4; ++rd) {
        int byteo = hi * 64 + rd * 16;
        bf16x8 v = *(const bf16x8*)(sO + q * 128 + (byteo ^ ((q & 7) << 4)));
        *(bf16x8*)(Og + ((size_t)b * 2048 + q0 + q) * 1024 + h * 64 + byteo / 2) = v;
      }
    }
  }
}

extern "C" void kernel_launch(void* const* d_in, const int* in_sizes, int n_in,
                              void* d_out, int out_size, void* d_ws, size_t ws_size,
                              hipStream_t stream) {
  const float* x = (const float*)d_in[0];
  const float* Wqkv = (const float*)d_in[1];
  const float* bqkv = (const float*)d_in[2];
  const float* Wproj = (const float*)d_in[3];
  const float* bproj = (const float*)d_in[4];
  float* out = (float*)d_out;
  char* ws = (char*)d_ws;

  bf16* XB = (bf16*)(ws + 0);            // 8 MB x_bf16 [4096][1024]; reused as attn-out
  bf16* WQT = (bf16*)(ws + 8388608);     // 6 MB WqkvT (permuted, Q pre-scaled) [3072][1024]
  float* BQP = (float*)(ws + 14680064);  // 16 KB permuted bias (Q part pre-scaled)
  bf16* WPT = (bf16*)(ws + 14696448);    // 2 MB WprojT [1024][1024]
  bf16* Q = (bf16*)(ws + 16793600);      // 8 MB [2][16][2048][64]
  bf16* K = (bf16*)(ws + 25182208);      // 8 MB (contiguous after Q: qk base + 4194304 elems)
  bf16* VT = (bf16*)(ws + 33570816);     // 8 MB [2][16][64][2048] (written directly by gemm<0>)
  bf16* AO = XB;
  (void)K;
  (void)ws_size;

  k_prep_all<<<2316, 256, 0, stream>>>(x, Wqkv, bqkv, Wproj, XB, WQT, WPT, BQP);
  k_gemm_qkv<<<768, 256, 0, stream>>>(XB, WQT, BQP, Q, VT);
  k_attn<<<256, 512, 0, stream>>>(Q, Q + 4194304, VT, AO);
  k_gemm_proj<<<512, 256, 0, stream>>>(AO, WPT, bproj, out);
}

// Round 17
// 109.842 us; speedup vs baseline: 1.2722x; 1.0046x over previous
//
#include <hip/hip_runtime.h>
#include <hip/hip_bf16.h>
#include <stdint.h>

typedef __bf16 bf16;
typedef __attribute__((ext_vector_type(8))) __bf16 bf16x8;
typedef __attribute__((ext_vector_type(4))) __bf16 bf16x4;
typedef __attribute__((ext_vector_type(4))) float f32x4;
typedef __attribute__((ext_vector_type(16))) float f32x16;

#define MFMA16(a, b, c) __builtin_amdgcn_mfma_f32_16x16x32_bf16((a), (b), (c), 0, 0, 0)
#define MFMA32(a, b, c) __builtin_amdgcn_mfma_f32_32x32x16_bf16((a), (b), (c), 0, 0, 0)

// log2(e) / sqrt(1024)
#define QSCALE 0.045084220027780106f

__device__ __forceinline__ void glds16(const void* g, void* l) {
  __builtin_amdgcn_global_load_lds(
      (const __attribute__((address_space(1))) void*)g,
      (__attribute__((address_space(3))) void*)l, 16, 0, 0);
}

// swizzled 16B fragment read from a [rows][64] bf16 tile (128B rows, XOR-16 swizzle)
__device__ __forceinline__ bf16x8 ldsfrag(const unsigned char* base, int row, int colb) {
  return *(const bf16x8*)(base + row * 128 + (colb ^ ((row & 7) << 4)));
}

__device__ __forceinline__ uint32_t pkbf16(float a, float b) {
  uint32_t r;
  asm("v_cvt_pk_bf16_f32 %0, %1, %2" : "=v"(r) : "v"(a), "v"(b));
  return r;
}

// raw v_exp_f32: args here are far from the subnormal range, skip libm's fixup
__device__ __forceinline__ float fexp2(float x) {
#if __has_builtin(__builtin_amdgcn_exp2f)
  return __builtin_amdgcn_exp2f(x);
#else
  float r;
  asm("v_exp_f32 %0, %1" : "=v"(r) : "v"(x));
  return r;
#endif
}

__device__ __forceinline__ f32x16 zero16() {
  f32x16 v;
#pragma unroll
  for (int i = 0; i < 16; ++i) v[i] = 0.f;
  return v;
}

// ---------------- fused prep kernel: all 4 preps in one dispatch ----------------
template <int MODE>
__device__ __forceinline__ void prep_w_body(const float* __restrict__ W, bf16* __restrict__ WT,
                                            float (*tile)[256], int c0, int k0) {
  const int C = (MODE == 0) ? 3072 : 1024;
  const int lw = threadIdx.x & 63, w = threadIdx.x >> 6;
#pragma unroll
  for (int i = 0; i < 16; ++i) {
    int r = i * 4 + w;
    f32x4 v = *(const f32x4*)(W + (size_t)(k0 + r) * C + c0 + lw * 4);
    *(f32x4*)&tile[r][lw * 4] = v;
  }
  __syncthreads();
  const int c = c0 + threadIdx.x;
  int j;
  float sc = 1.0f;
  if (MODE == 0) {
    int h = c / 192, rem = c - h * 192, dd = rem / 3, wh = rem - dd * 3;
    j = wh * 1024 + h * 64 + dd;
    if (wh == 0) sc = QSCALE;
  } else {
    j = c;
  }
#pragma unroll
  for (int ch = 0; ch < 8; ++ch) {
    bf16x8 o;
#pragma unroll
    for (int i = 0; i < 8; ++i) o[i] = (bf16)(tile[ch * 8 + i][threadIdx.x] * sc);
    *(bf16x8*)(WT + (size_t)j * 1024 + k0 + ch * 8) = o;
  }
}

__global__ __launch_bounds__(256) void k_prep_all(const float* __restrict__ x,
                                                  const float* __restrict__ Wqkv,
                                                  const float* __restrict__ bqkv,
                                                  const float* __restrict__ Wproj,
                                                  bf16* __restrict__ xb, bf16* __restrict__ WQT,
                                                  bf16* __restrict__ WPT, float* __restrict__ bp) {
  __shared__ float tile[64][256];
  int bid = blockIdx.x;
  if (bid < 2048) {  // ---- x -> bf16 ----
    int gid = bid * 256 + threadIdx.x;
    const f32x4* xv = (const f32x4*)x;
    f32x4 a = xv[(size_t)gid * 2], b = xv[(size_t)gid * 2 + 1];
    bf16x8 o;
#pragma unroll
    for (int i = 0; i < 4; ++i) { o[i] = (bf16)a[i]; o[i + 4] = (bf16)b[i]; }
    *(bf16x8*)(xb + (size_t)gid * 8) = o;
    return;
  }
  bid -= 2048;
  if (bid < 192) {  // ---- Wqkv transpose+permute ----
    prep_w_body<0>(Wqkv, WQT, tile, (bid % 12) * 256, (bid / 12) * 64);
    return;
  }
  bid -= 192;
  if (bid < 64) {  // ---- Wproj transpose ----
    prep_w_body<1>(Wproj, WPT, tile, (bid % 4) * 256, (bid / 4) * 64);
    return;
  }
  bid -= 64;
  {  // ---- bias permute (12 blocks) ----
    int gid = bid * 256 + threadIdx.x;  // j in [0,3072)
    int wj = gid >> 10, rr = gid & 1023, hh = rr >> 6, d2 = rr & 63;
    float v = bqkv[hh * 192 + d2 * 3 + wj];
    bp[gid] = (wj == 0) ? v * QSCALE : v;
  }
}

// ---------------- 256x256 8-phase QKV GEMM (r17, T3+T4 port of the m201 template) ----------------
// 512 threads = 8 waves (2 wr x 4 wc); per-wave output 128x64 (acc[8][4] f32x4 = 128 VGPR).
// LDS 128KB: A[2 buf][256 rows][128B] + B same; rows XOR-16 swizzled (proven brick).
// Per K-tile (BK=64, 16 tiles): 4 phases. Phase P: {ds_read A-frags mi {2P,2P+1} (+ all B at P0)
// | stage one half-tile | [vmcnt(4) at P3] | s_barrier | lgkmcnt(0) | 16 MFMA | s_barrier}.
// Stage stream: A(t+1) at phases 0,1 -> buf[q]; B(t+2) at phases 1,2 -> buf[p]; vmcnt(4) leaves
// B(t+2) in flight across the iteration boundary (T4: never drain to 0 in the loop).
// Per-element K-chain (kt 0..15, ks 0..1, MFMA16, bias, scatter) identical to r16 -> bit-exact.
__global__ __launch_bounds__(512, 1) void k_gemm_qkv8(const bf16* __restrict__ A,
                                                      const bf16* __restrict__ BT,
                                                      const float* __restrict__ bias,
                                                      bf16* __restrict__ qk, bf16* __restrict__ vt) {
  __shared__ __align__(16) unsigned char smem[131072];
  unsigned char* sA = smem;            // [2][256][128]
  unsigned char* sB = smem + 65536;    // [2][256][128]
  const int tid = threadIdx.x;
  const int l = tid & 63, w = tid >> 6, g = l >> 4, l15 = l & 15;
  const int wr = w >> 2, wc = w & 3;
  const int wg = (blockIdx.x & 7) * 24 + (blockIdx.x >> 3);  // XCD-chunked, 192 = 8 x 24
  const int bn = wg % 12, bm = wg / 12;
  const unsigned char* Ab = (const unsigned char*)A + (size_t)bm * 256 * 2048;
  const unsigned char* Bb = (const unsigned char*)BT + (size_t)bn * 256 * 2048;

  f32x4 acc[8][4];
#pragma unroll
  for (int mi = 0; mi < 8; ++mi)
#pragma unroll
    for (int ni = 0; ni < 4; ++ni) acc[mi][ni] = (f32x4){0.f, 0.f, 0.f, 0.f};

  // staging coords: one half-tile (128 rows x 128B = 16KB) = 2 glds16/thread
  const int co0 = tid * 16, co1 = tid * 16 + 8192;
  const int r0 = co0 >> 7, r1 = co1 >> 7;
  const int s0 = (co0 & 127) ^ ((r0 & 7) << 4), s1 = (co1 & 127) ^ ((r1 & 7) << 4);

// stage half H_ of K-tile KT_ of operand (gbase_ rows x 2048B) into ldsb_ buffer BUF_
#define STG(gbase_, KT_, H_, ldsb_, BUF_)                                                   \
  do {                                                                                      \
    glds16((gbase_) + (size_t)((H_)*128 + r0) * 2048 + (size_t)(KT_)*128 + s0,              \
           (ldsb_) + (BUF_)*32768 + (H_)*16384 + co0);                                      \
    glds16((gbase_) + (size_t)((H_)*128 + r1) * 2048 + (size_t)(KT_)*128 + s1,              \
           (ldsb_) + (BUF_)*32768 + (H_)*16384 + co1);                                      \
  } while (0)

#define VMWAIT(n)                                                                           \
  do {                                                                                      \
    asm volatile("s_waitcnt vmcnt(" #n ")" ::: "memory");                                   \
    __builtin_amdgcn_sched_barrier(0);                                                      \
  } while (0)
#define RAWBAR()                                                                            \
  do {                                                                                      \
    __builtin_amdgcn_sched_barrier(0);                                                      \
    __builtin_amdgcn_s_barrier();                                                           \
    __builtin_amdgcn_sched_barrier(0);                                                      \
  } while (0)
#define LGKM0()                                                                             \
  do {                                                                                      \
    asm volatile("s_waitcnt lgkmcnt(0)" ::: "memory");                                      \
    __builtin_amdgcn_sched_barrier(0);                                                      \
  } while (0)

// 16 MFMA of phase P_ (mi pair {2P,2P+1}), ks inner-sequential per acc element
#define PH_MFMA(P_)                                                                         \
  do {                                                                                      \
    __builtin_amdgcn_s_setprio(1);                                                          \
    _Pragma("unroll") for (int ks = 0; ks < 2; ++ks)                                        \
      _Pragma("unroll") for (int m2 = 0; m2 < 2; ++m2)                                      \
        _Pragma("unroll") for (int ni = 0; ni < 4; ++ni)                                    \
          acc[(P_)*2 + m2][ni] = MFMA16(af[m2][ks], bfr[ni][ks], acc[(P_)*2 + m2][ni]);     \
    __builtin_amdgcn_s_setprio(0);                                                          \
  } while (0)

#define RD_AF(P_, BUF_)                                                                     \
  do {                                                                                      \
    _Pragma("unroll") for (int m2 = 0; m2 < 2; ++m2)                                        \
      _Pragma("unroll") for (int ks = 0; ks < 2; ++ks)                                      \
        af[m2][ks] = ldsfrag(sA + (BUF_)*32768, wr * 128 + ((P_)*2 + m2) * 16 + l15,        \
                             ks * 64 + g * 16);                                             \
  } while (0)

// one K-tile iteration: T_=tile index (runtime ok), PBUF_=T_&1 (literal), DOA_: stage A(T_+1),
// DOB_: stage B(T_+2), FULLVM_: 1 -> vmcnt(4), 0 -> vmcnt(0)
#define ITER(T_, PBUF_, DOA_, DOB_, FULLVM_)                                                \
  do {                                                                                      \
    bf16x8 bfr[4][2];                                                                       \
    bf16x8 af[2][2];                                                                        \
    /* phase 0: read all B-frags + A mi{0,1}; stage A-h0(T+1) */                            \
    _Pragma("unroll") for (int ni = 0; ni < 4; ++ni)                                        \
      _Pragma("unroll") for (int ks = 0; ks < 2; ++ks)                                      \
        bfr[ni][ks] = ldsfrag(sB + (PBUF_)*32768, wc * 64 + ni * 16 + l15, ks * 64 + g * 16); \
    RD_AF(0, PBUF_);                                                                        \
    if (DOA_) STG(Ab, (T_) + 1, 0, sA, 1 - (PBUF_));                                        \
    RAWBAR();                                                                               \
    LGKM0();                                                                                \
    PH_MFMA(0);                                                                             \
    RAWBAR();                                                                               \
    /* phase 1: A mi{2,3}; stage A-h1(T+1), B-h0(T+2) */                                    \
    RD_AF(1, PBUF_);                                                                        \
    if (DOA_) STG(Ab, (T_) + 1, 1, sA, 1 - (PBUF_));                                        \
    if (DOB_) STG(Bb, (T_) + 2, 0, sB, (PBUF_));                                            \
    RAWBAR();                                                                               \
    LGKM0();                                                                                \
    PH_MFMA(1);                                                                             \
    RAWBAR();                                                                               \
    /* phase 2: A mi{4,5}; stage B-h1(T+2) */                                               \
    RD_AF(2, PBUF_);                                                                        \
    if (DOB_) STG(Bb, (T_) + 2, 1, sB, (PBUF_));                                            \
    RAWBAR();                                                                               \
    LGKM0();                                                                                \
    PH_MFMA(2);                                                                             \
    RAWBAR();                                                                               \
    /* phase 3: A mi{6,7}; counted wait (leaves B(T+2) in flight) */                        \
    RD_AF(3, PBUF_);                                                                        \
    if (FULLVM_) { VMWAIT(4); } else { VMWAIT(0); }                                         \
    RAWBAR();                                                                               \
    LGKM0();                                                                                \
    PH_MFMA(3);                                                                             \
    RAWBAR();                                                                               \
  } while (0)

  // ---- prologue: tile0 (A+B) + B(1); wait tile0, leave B(1) in flight ----
  STG(Ab, 0, 0, sA, 0);
  STG(Ab, 0, 1, sA, 0);
  STG(Bb, 0, 0, sB, 0);
  STG(Bb, 0, 1, sB, 0);
  STG(Bb, 1, 0, sB, 1);
  STG(Bb, 1, 1, sB, 1);
  VMWAIT(4);
  RAWBAR();

  // ---- 16 K-tiles ----
  for (int t2 = 0; t2 < 7; ++t2) {
    const int t = t2 * 2;
    ITER(t, 0, 1, 1, 1);
    ITER(t + 1, 1, 1, 1, 1);
  }
  ITER(14, 0, 1, 0, 0);
  ITER(15, 1, 0, 0, 0);

#undef STG
#undef VMWAIT
#undef RAWBAR
#undef LGKM0
#undef PH_MFMA
#undef RD_AF
#undef ITER

  // ---- epilogue: bias + QKV scatter (same mapping as r16 -> bit-exact) ----
#pragma unroll
  for (int ni = 0; ni < 4; ++ni) {
    int j = bn * 256 + wc * 64 + ni * 16 + l15;
    float bj = bias[j];
    int which = j >> 10, r = j & 1023, h = r >> 6, dd = r & 63;
#pragma unroll
    for (int mi = 0; mi < 8; ++mi) {
      int m0 = bm * 256 + wr * 128 + mi * 16 + g * 4;  // C/D: row=(l>>4)*4+reg, col=l&15
      float v[4];
#pragma unroll
      for (int rr = 0; rr < 4; ++rr) v[rr] = acc[mi][ni][rr] + bj;
      int b = m0 >> 11, nn = m0 & 2047;
      if (which < 2) {
#pragma unroll
        for (int rr = 0; rr < 4; ++rr)
          qk[(size_t)which * 4194304 + (((size_t)b * 16 + h) * 2048 + nn + rr) * 64 + dd] = (bf16)v[rr];
      } else {
        bf16x4 pw = {(bf16)v[0], (bf16)v[1], (bf16)v[2], (bf16)v[3]};
        *(bf16x4*)(vt + (((size_t)b * 16 + h) * 64 + dd) * 2048 + nn) = pw;
      }
    }
  }
}

// ---------------- 64x128 proj GEMM (r16, frozen) ----------------
__global__ __launch_bounds__(256) void k_gemm_proj(const bf16* __restrict__ A, const bf16* __restrict__ BT,
                                                   const float* __restrict__ bias, float* __restrict__ outf) {
  __shared__ __align__(16) unsigned char sA[8192];   // [64][64] bf16, swizzled 128B rows
  __shared__ __align__(16) unsigned char sB[16384];  // [128][64]
  const int tid = threadIdx.x;
  const int l = tid & 63, w = tid >> 6, g = l >> 4, l15 = l & 15;
  const int wg = (blockIdx.x & 7) * 64 + (blockIdx.x >> 3);
  const int bn = wg & 7, bm = wg >> 3;
  const unsigned char* Ab = (const unsigned char*)A + (size_t)bm * 64 * 2048;
  const unsigned char* Bb = (const unsigned char*)BT + (size_t)bn * 128 * 2048;
  f32x4 acc[4][2];
#pragma unroll
  for (int mi = 0; mi < 4; ++mi)
#pragma unroll
    for (int ni = 0; ni < 2; ++ni) acc[mi][ni] = (f32x4){0.f, 0.f, 0.f, 0.f};

  for (int kt = 0; kt < 16; ++kt) {
    const int k0b = kt * 128;
#pragma unroll
    for (int p = 0; p < 2; ++p) {  // A: 8KB = 2 x 16B/thread
      int co = (p * 256 + tid) * 16;
      int row = co >> 7;
      int sw = (co & 127) ^ ((row & 7) << 4);
      glds16(Ab + (size_t)row * 2048 + k0b + sw, sA + co);
    }
#pragma unroll
    for (int p = 0; p < 4; ++p) {  // B: 16KB = 4 x 16B/thread
      int co = (p * 256 + tid) * 16;
      int row = co >> 7;
      int sw = (co & 127) ^ ((row & 7) << 4);
      glds16(Bb + (size_t)row * 2048 + k0b + sw, sB + co);
    }
    __syncthreads();
#pragma unroll
    for (int ks = 0; ks < 2; ++ks) {
      bf16x8 af[4], bfr[2];
#pragma unroll
      for (int mi = 0; mi < 4; ++mi) af[mi] = ldsfrag(sA, mi * 16 + l15, ks * 64 + g * 16);
#pragma unroll
      for (int ni = 0; ni < 2; ++ni) bfr[ni] = ldsfrag(sB, w * 32 + ni * 16 + l15, ks * 64 + g * 16);
      __builtin_amdgcn_s_setprio(1);
#pragma unroll
      for (int mi = 0; mi < 4; ++mi)
#pragma unroll
        for (int ni = 0; ni < 2; ++ni) acc[mi][ni] = MFMA16(af[mi], bfr[ni], acc[mi][ni]);
      __builtin_amdgcn_s_setprio(0);
    }
    __syncthreads();
  }
#pragma unroll
  for (int ni = 0; ni < 2; ++ni) {
    int j = bn * 128 + w * 32 + ni * 16 + l15;
    float bj = bias[j];
#pragma unroll
    for (int mi = 0; mi < 4; ++mi) {
      int m0 = bm * 64 + mi * 16 + g * 4;
#pragma unroll
      for (int rr = 0; rr < 4; ++rr) outf[(size_t)(m0 + rr) * 1024 + j] = acc[mi][ni][rr] + bj;
    }
  }
}

// ---------------- flash attention (r9/r14 structure, frozen; canary 9.766e-4) ----------------
__global__ __launch_bounds__(512, 1) void k_attn(const bf16* __restrict__ Qg, const bf16* __restrict__ Kg,
                                                 const bf16* __restrict__ VTg, bf16* __restrict__ Og) {
  __shared__ __align__(16) unsigned char smem[67584];
  const int tid = threadIdx.x;
  const int l = tid & 63, w = tid >> 6;
  const int q = l & 31, hi = l >> 5;
  const int g = w >> 2, wl = w & 3;
  const int stid = tid & 255;

  const int bid = blockIdx.x;                  // 256 blocks
  const int wg = (bid & 7) * 32 + (bid >> 3);  // XCD-chunked: 4 consecutive bh per XCD
  const int bh = wg >> 3;
  const int q0w = (wg & 7) * 256 + wl * 64;    // this wave's 64 q-rows

  bf16x8 qf[2][4];
#pragma unroll
  for (int qt = 0; qt < 2; ++qt)
#pragma unroll
    for (int ks = 0; ks < 4; ++ks)
      qf[qt][ks] = *(const bf16x8*)(Qg + ((size_t)bh * 2048 + q0w + qt * 32 + q) * 64 + ks * 16 + hi * 8);

  f32x16 oacc[2][2];
#pragma unroll
  for (int qt = 0; qt < 2; ++qt) { oacc[qt][0] = zero16(); oacc[qt][1] = zero16(); }
  float lrun4[2][4] = {{0.f, 0.f, 0.f, 0.f}, {0.f, 0.f, 0.f, 0.f}};
  bf16x8 pb[2][4];

  const unsigned char* Kb = (const unsigned char*)Kg + (size_t)bh * 262144 + (size_t)g * 131072;
  const unsigned char* Vb = (const unsigned char*)VTg + (size_t)bh * 262144 + (size_t)g * 2048;
  unsigned char* sKg = smem + g * 16384;
  unsigned char* sVg = smem + 32768 + g * 16384;

  const int co0 = stid * 16, co1 = (256 + stid) * 16;
  const int row0 = co0 >> 7, row1 = co1 >> 7;
  const int sw0 = (co0 & 127) ^ ((row0 & 7) << 4), sw1 = (co1 & 127) ^ ((row1 & 7) << 4);

#define STAGE_K(kb_, buf_)                                                        \
  do {                                                                            \
    const unsigned char* Ksrc = Kb + (size_t)(kb_) * 8192;                        \
    glds16(Ksrc + (co0 & ~127) + sw0, sKg + (buf_) * 8192 + co0);                 \
    glds16(Ksrc + (co1 & ~127) + sw1, sKg + (buf_) * 8192 + co1);                 \
  } while (0)
#define STAGE_V(kb_, buf_)                                                        \
  do {                                                                            \
    glds16(Vb + (size_t)row0 * 4096 + (size_t)(kb_) * 128 + sw0, sVg + (buf_) * 8192 + co0); \
    glds16(Vb + (size_t)row1 * 4096 + (size_t)(kb_) * 128 + sw1, sVg + (buf_) * 8192 + co1); \
  } while (0)

#define QK_EXP_PACK(kbase_)                                                       \
  do {                                                                            \
    _Pragma("unroll") for (int kt = 0; kt < 2; ++kt) {                            \
      bf16x8 kf[4];                                                               \
      _Pragma("unroll") for (int ks = 0; ks < 4; ++ks)                            \
        kf[ks] = ldsfrag((kbase_), kt * 32 + q, ks * 32 + hi * 16);               \
      _Pragma("unroll") for (int qt = 0; qt < 2; ++qt) {                          \
        f32x16 sacc = zero16();                                                   \
        __builtin_amdgcn_s_setprio(1);                                            \
        _Pragma("unroll") for (int ks = 0; ks < 4; ++ks)                          \
          sacc = MFMA32(kf[ks], qf[qt][ks], sacc);                                \
        __builtin_amdgcn_s_setprio(0);                                            \
        float pe[16];                                                             \
        _Pragma("unroll") for (int r = 0; r < 16; ++r) pe[r] = fexp2(sacc[r]);    \
        _Pragma("unroll") for (int m = 0; m < 4; ++m)                             \
          _Pragma("unroll") for (int j = 0; j < 4; ++j) lrun4[qt][j] += pe[4 * m + j]; \
        uint32_t c[4][2];                                                         \
        _Pragma("unroll") for (int m = 0; m < 4; ++m) {                           \
          c[m][0] = pkbf16(pe[4 * m], pe[4 * m + 1]);                             \
          c[m][1] = pkbf16(pe[4 * m + 2], pe[4 * m + 3]);                         \
        }                                                                         \
        _Pragma("unroll") for (int s = 0; s < 2; ++s) {                           \
          uint32_t x0 = c[2 * s][0], y0 = c[2 * s + 1][0];                        \
          uint32_t x1 = c[2 * s][1], y1 = c[2 * s + 1][1];                        \
          asm("v_permlane32_swap_b32 %0, %1" : "+v"(x0), "+v"(y0));               \
          asm("v_permlane32_swap_b32 %0, %1" : "+v"(x1), "+v"(y1));               \
          union { uint32_t u[4]; bf16x8 v; } bfr;                                 \
          bfr.u[0] = x0; bfr.u[1] = x1; bfr.u[2] = y0; bfr.u[3] = y1;             \
          pb[qt][kt * 2 + s] = bfr.v;                                             \
        }                                                                         \
      }                                                                           \
    }                                                                             \
  } while (0)

#define PV_TILE(vbase_)                                                           \
  do {                                                                            \
    __builtin_amdgcn_s_setprio(1);                                                \
    _Pragma("unroll") for (int ks = 0; ks < 4; ++ks)                              \
      _Pragma("unroll") for (int dt = 0; dt < 2; ++dt) {                          \
        bf16x8 vf = ldsfrag((vbase_), dt * 32 + q, ks * 32 + hi * 16);            \
        _Pragma("unroll") for (int qtp = 0; qtp < 2; ++qtp)                       \
          oacc[qtp][dt] = MFMA32(vf, pb[qtp][ks], oacc[qtp][dt]);                 \
      }                                                                           \
    __builtin_amdgcn_s_setprio(0);                                                \
  } while (0)

  STAGE_K(0, 0);
  STAGE_V(0, 0);
  __syncthreads();
  STAGE_K(1, 1);
  QK_EXP_PACK(sKg);
  __syncthreads();
  int cur = 0;

  for (int kb = 0; kb < 15; ++kb) {
    const int nxt = cur ^ 1;
    if (kb < 14) STAGE_K(kb + 2, cur);
    STAGE_V(kb + 1, nxt);
    PV_TILE(sVg + cur * 8192);
    QK_EXP_PACK(sKg + nxt * 8192);
    __syncthreads();
    cur = nxt;
  }
  PV_TILE(sVg + cur * 8192);

#undef STAGE_K
#undef STAGE_V
#undef QK_EXP_PACK
#undef PV_TILE

  float lrun[2];
#pragma unroll
  for (int qt = 0; qt < 2; ++qt)
    lrun[qt] = (lrun4[qt][0] + lrun4[qt][1]) + (lrun4[qt][2] + lrun4[qt][3]);

  float* mbuf = (float*)smem;
  float* lb = (float*)(smem + 65536);
  if (g == 1) {
#pragma unroll
    for (int qt = 0; qt < 2; ++qt) {
#pragma unroll
      for (int dt = 0; dt < 2; ++dt)
#pragma unroll
        for (int r = 0; r < 16; ++r)
          mbuf[((wl * 64 + qt * 32 + dt * 16 + r) << 6) + l] = oacc[qt][dt][r];
      lb[(wl * 2 + qt) * 64 + l] = lrun[qt];
    }
  }
  __syncthreads();
  if (g == 0) {
#pragma unroll
    for (int qt = 0; qt < 2; ++qt)
#pragma unroll
      for (int dt = 0; dt < 2; ++dt)
#pragma unroll
        for (int r = 0; r < 16; ++r)
          oacc[qt][dt][r] += mbuf[((wl * 64 + qt * 32 + dt * 16 + r) << 6) + l];
  }
  __syncthreads();
  if (g == 0) {
    const int b = bh >> 4, h = bh & 15;
    unsigned char* sO = smem + 32768 + wl * 4096;
#pragma unroll
    for (int qt = 0; qt < 2; ++qt) {
      float lr = lrun[qt] + lb[(wl * 2 + qt) * 64 + l];
      float ps = lr + __shfl_xor(lr, 32);
      float linv = 1.0f / ps;
#pragma unroll
      for (int dt = 0; dt < 2; ++dt)
#pragma unroll
        for (int m = 0; m < 4; ++m) {
          uint32_t b0 = pkbf16(oacc[qt][dt][4 * m] * linv, oacc[qt][dt][4 * m + 1] * linv);
          uint32_t b1 = pkbf16(oacc[qt][dt][4 * m + 2] * linv, oacc[qt][dt][4 * m + 3] * linv);
          int byteo = (dt * 64 + m * 16 + hi * 8) ^ ((q & 7) << 4);
          uint32_t* dst = (uint32_t*)(sO + q * 128 + byteo);
          dst[0] = b0; dst[1] = b1;
        }
      const int q0 = q0w + qt * 32;
#pragma unroll
      for (int rd = 0; rd < 4; ++rd) {
        int byteo = hi * 64 + rd * 16;
        bf16x8 v = *(const bf16x8*)(sO + q * 128 + (byteo ^ ((q & 7) << 4)));
        *(bf16x8*)(Og + ((size_t)b * 2048 + q0 + q) * 1024 + h * 64 + byteo / 2) = v;
      }
    }
  }
}

extern "C" void kernel_launch(void* const* d_in, const int* in_sizes, int n_in,
                              void* d_out, int out_size, void* d_ws, size_t ws_size,
                              hipStream_t stream) {
  const float* x = (const float*)d_in[0];
  const float* Wqkv = (const float*)d_in[1];
  const float* bqkv = (const float*)d_in[2];
  const float* Wproj = (const float*)d_in[3];
  const float* bproj = (const float*)d_in[4];
  float* out = (float*)d_out;
  char* ws = (char*)d_ws;

  bf16* XB = (bf16*)(ws + 0);            // 8 MB x_bf16 [4096][1024]; reused as attn-out
  bf16* WQT = (bf16*)(ws + 8388608);     // 6 MB WqkvT (permuted, Q pre-scaled) [3072][1024]
  float* BQP = (float*)(ws + 14680064);  // 16 KB permuted bias (Q part pre-scaled)
  bf16* WPT = (bf16*)(ws + 14696448);    // 2 MB WprojT [1024][1024]
  bf16* Q = (bf16*)(ws + 16793600);      // 8 MB [2][16][2048][64]
  bf16* K = (bf16*)(ws + 25182208);      // 8 MB (contiguous after Q: qk base + 4194304 elems)
  bf16* VT = (bf16*)(ws + 33570816);     // 8 MB [2][16][64][2048] (written directly by gemm)
  bf16* AO = XB;
  (void)K;
  (void)ws_size;

  k_prep_all<<<2316, 256, 0, stream>>>(x, Wqkv, bqkv, Wproj, XB, WQT, WPT, BQP);
  k_gemm_qkv8<<<192, 512, 0, stream>>>(XB, WQT, BQP, Q, VT);
  k_attn<<<256, 512, 0, stream>>>(Q, Q + 4194304, VT, AO);
  k_gemm_proj<<<512, 256, 0, stream>>>(AO, WPT, bproj, out);
}

// Round 18
// 109.028 us; speedup vs baseline: 1.2817x; 1.0075x over previous
//
#include <hip/hip_runtime.h>
#include <hip/hip_bf16.h>
#include <stdint.h>

typedef __bf16 bf16;
typedef __attribute__((ext_vector_type(8))) __bf16 bf16x8;
typedef __attribute__((ext_vector_type(4))) __bf16 bf16x4;
typedef __attribute__((ext_vector_type(4))) float f32x4;
typedef __attribute__((ext_vector_type(16))) float f32x16;

#define MFMA16(a, b, c) __builtin_amdgcn_mfma_f32_16x16x32_bf16((a), (b), (c), 0, 0, 0)
#define MFMA32(a, b, c) __builtin_amdgcn_mfma_f32_32x32x16_bf16((a), (b), (c), 0, 0, 0)

// log2(e) / sqrt(1024)
#define QSCALE 0.045084220027780106f

__device__ __forceinline__ void glds16(const void* g, void* l) {
  __builtin_amdgcn_global_load_lds(
      (const __attribute__((address_space(1))) void*)g,
      (__attribute__((address_space(3))) void*)l, 16, 0, 0);
}

// swizzled 16B fragment read from a [rows][64] bf16 tile (128B rows, XOR-16 swizzle)
__device__ __forceinline__ bf16x8 ldsfrag(const unsigned char* base, int row, int colb) {
  return *(const bf16x8*)(base + row * 128 + (colb ^ ((row & 7) << 4)));
}

__device__ __forceinline__ uint32_t pkbf16(float a, float b) {
  uint32_t r;
  asm("v_cvt_pk_bf16_f32 %0, %1, %2" : "=v"(r) : "v"(a), "v"(b));
  return r;
}

// raw v_exp_f32: args here are far from the subnormal range, skip libm's fixup
__device__ __forceinline__ float fexp2(float x) {
#if __has_builtin(__builtin_amdgcn_exp2f)
  return __builtin_amdgcn_exp2f(x);
#else
  float r;
  asm("v_exp_f32 %0, %1" : "=v"(r) : "v"(x));
  return r;
#endif
}

__device__ __forceinline__ f32x16 zero16() {
  f32x16 v;
#pragma unroll
  for (int i = 0; i < 16; ++i) v[i] = 0.f;
  return v;
}

// ---------------- fused prep kernel: all 4 preps in one dispatch ----------------
template <int MODE>
__device__ __forceinline__ void prep_w_body(const float* __restrict__ W, bf16* __restrict__ WT,
                                            float (*tile)[256], int c0, int k0) {
  const int C = (MODE == 0) ? 3072 : 1024;
  const int lw = threadIdx.x & 63, w = threadIdx.x >> 6;
#pragma unroll
  for (int i = 0; i < 16; ++i) {
    int r = i * 4 + w;
    f32x4 v = *(const f32x4*)(W + (size_t)(k0 + r) * C + c0 + lw * 4);
    *(f32x4*)&tile[r][lw * 4] = v;
  }
  __syncthreads();
  const int c = c0 + threadIdx.x;
  int j;
  float sc = 1.0f;
  if (MODE == 0) {
    int h = c / 192, rem = c - h * 192, dd = rem / 3, wh = rem - dd * 3;
    j = wh * 1024 + h * 64 + dd;
    if (wh == 0) sc = QSCALE;
  } else {
    j = c;
  }
#pragma unroll
  for (int ch = 0; ch < 8; ++ch) {
    bf16x8 o;
#pragma unroll
    for (int i = 0; i < 8; ++i) o[i] = (bf16)(tile[ch * 8 + i][threadIdx.x] * sc);
    *(bf16x8*)(WT + (size_t)j * 1024 + k0 + ch * 8) = o;
  }
}

__global__ __launch_bounds__(256) void k_prep_all(const float* __restrict__ x,
                                                  const float* __restrict__ Wqkv,
                                                  const float* __restrict__ bqkv,
                                                  const float* __restrict__ Wproj,
                                                  bf16* __restrict__ xb, bf16* __restrict__ WQT,
                                                  bf16* __restrict__ WPT, float* __restrict__ bp) {
  __shared__ float tile[64][256];
  int bid = blockIdx.x;
  if (bid < 2048) {  // ---- x -> bf16 ----
    int gid = bid * 256 + threadIdx.x;
    const f32x4* xv = (const f32x4*)x;
    f32x4 a = xv[(size_t)gid * 2], b = xv[(size_t)gid * 2 + 1];
    bf16x8 o;
#pragma unroll
    for (int i = 0; i < 4; ++i) { o[i] = (bf16)a[i]; o[i + 4] = (bf16)b[i]; }
    *(bf16x8*)(xb + (size_t)gid * 8) = o;
    return;
  }
  bid -= 2048;
  if (bid < 192) {  // ---- Wqkv transpose+permute ----
    prep_w_body<0>(Wqkv, WQT, tile, (bid % 12) * 256, (bid / 12) * 64);
    return;
  }
  bid -= 192;
  if (bid < 64) {  // ---- Wproj transpose ----
    prep_w_body<1>(Wproj, WPT, tile, (bid % 4) * 256, (bid / 4) * 64);
    return;
  }
  bid -= 64;
  {  // ---- bias permute (12 blocks) ----
    int gid = bid * 256 + threadIdx.x;  // j in [0,3072)
    int wj = gid >> 10, rr = gid & 1023, hh = rr >> 6, d2 = rr & 63;
    float v = bqkv[hh * 192 + d2 * 3 + wj];
    bp[gid] = (wj == 0) ? v * QSCALE : v;
  }
}

// ---------------- 256x256 8-phase QKV GEMM (r17, kept: timed-best) ----------------
__global__ __launch_bounds__(512, 1) void k_gemm_qkv8(const bf16* __restrict__ A,
                                                      const bf16* __restrict__ BT,
                                                      const float* __restrict__ bias,
                                                      bf16* __restrict__ qk, bf16* __restrict__ vt) {
  __shared__ __align__(16) unsigned char smem[131072];
  unsigned char* sA = smem;            // [2][256][128]
  unsigned char* sB = smem + 65536;    // [2][256][128]
  const int tid = threadIdx.x;
  const int l = tid & 63, w = tid >> 6, g = l >> 4, l15 = l & 15;
  const int wr = w >> 2, wc = w & 3;
  const int wg = (blockIdx.x & 7) * 24 + (blockIdx.x >> 3);  // XCD-chunked, 192 = 8 x 24
  const int bn = wg % 12, bm = wg / 12;
  const unsigned char* Ab = (const unsigned char*)A + (size_t)bm * 256 * 2048;
  const unsigned char* Bb = (const unsigned char*)BT + (size_t)bn * 256 * 2048;

  f32x4 acc[8][4];
#pragma unroll
  for (int mi = 0; mi < 8; ++mi)
#pragma unroll
    for (int ni = 0; ni < 4; ++ni) acc[mi][ni] = (f32x4){0.f, 0.f, 0.f, 0.f};

  const int co0 = tid * 16, co1 = tid * 16 + 8192;
  const int r0 = co0 >> 7, r1 = co1 >> 7;
  const int s0 = (co0 & 127) ^ ((r0 & 7) << 4), s1 = (co1 & 127) ^ ((r1 & 7) << 4);

#define STG(gbase_, KT_, H_, ldsb_, BUF_)                                                   \
  do {                                                                                      \
    glds16((gbase_) + (size_t)((H_)*128 + r0) * 2048 + (size_t)(KT_)*128 + s0,              \
           (ldsb_) + (BUF_)*32768 + (H_)*16384 + co0);                                      \
    glds16((gbase_) + (size_t)((H_)*128 + r1) * 2048 + (size_t)(KT_)*128 + s1,              \
           (ldsb_) + (BUF_)*32768 + (H_)*16384 + co1);                                      \
  } while (0)

#define VMWAIT(n)                                                                           \
  do {                                                                                      \
    asm volatile("s_waitcnt vmcnt(" #n ")" ::: "memory");                                   \
    __builtin_amdgcn_sched_barrier(0);                                                      \
  } while (0)
#define RAWBAR()                                                                            \
  do {                                                                                      \
    __builtin_amdgcn_sched_barrier(0);                                                      \
    __builtin_amdgcn_s_barrier();                                                           \
    __builtin_amdgcn_sched_barrier(0);                                                      \
  } while (0)
#define LGKM0()                                                                             \
  do {                                                                                      \
    asm volatile("s_waitcnt lgkmcnt(0)" ::: "memory");                                      \
    __builtin_amdgcn_sched_barrier(0);                                                      \
  } while (0)

#define PH_MFMA(P_)                                                                         \
  do {                                                                                      \
    __builtin_amdgcn_s_setprio(1);                                                          \
    _Pragma("unroll") for (int ks = 0; ks < 2; ++ks)                                        \
      _Pragma("unroll") for (int m2 = 0; m2 < 2; ++m2)                                      \
        _Pragma("unroll") for (int ni = 0; ni < 4; ++ni)                                    \
          acc[(P_)*2 + m2][ni] = MFMA16(af[m2][ks], bfr[ni][ks], acc[(P_)*2 + m2][ni]);     \
    __builtin_amdgcn_s_setprio(0);                                                          \
  } while (0)

#define RD_AF(P_, BUF_)                                                                     \
  do {                                                                                      \
    _Pragma("unroll") for (int m2 = 0; m2 < 2; ++m2)                                        \
      _Pragma("unroll") for (int ks = 0; ks < 2; ++ks)                                      \
        af[m2][ks] = ldsfrag(sA + (BUF_)*32768, wr * 128 + ((P_)*2 + m2) * 16 + l15,        \
                             ks * 64 + g * 16);                                             \
  } while (0)

#define ITER(T_, PBUF_, DOA_, DOB_, FULLVM_)                                                \
  do {                                                                                      \
    bf16x8 bfr[4][2];                                                                       \
    bf16x8 af[2][2];                                                                        \
    _Pragma("unroll") for (int ni = 0; ni < 4; ++ni)                                        \
      _Pragma("unroll") for (int ks = 0; ks < 2; ++ks)                                      \
        bfr[ni][ks] = ldsfrag(sB + (PBUF_)*32768, wc * 64 + ni * 16 + l15, ks * 64 + g * 16); \
    RD_AF(0, PBUF_);                                                                        \
    if (DOA_) STG(Ab, (T_) + 1, 0, sA, 1 - (PBUF_));                                        \
    RAWBAR();                                                                               \
    LGKM0();                                                                                \
    PH_MFMA(0);                                                                             \
    RAWBAR();                                                                               \
    RD_AF(1, PBUF_);                                                                        \
    if (DOA_) STG(Ab, (T_) + 1, 1, sA, 1 - (PBUF_));                                        \
    if (DOB_) STG(Bb, (T_) + 2, 0, sB, (PBUF_));                                            \
    RAWBAR();                                                                               \
    LGKM0();                                                                                \
    PH_MFMA(1);                                                                             \
    RAWBAR();                                                                               \
    RD_AF(2, PBUF_);                                                                        \
    if (DOB_) STG(Bb, (T_) + 2, 1, sB, (PBUF_));                                            \
    RAWBAR();                                                                               \
    LGKM0();                                                                                \
    PH_MFMA(2);                                                                             \
    RAWBAR();                                                                               \
    RD_AF(3, PBUF_);                                                                        \
    if (FULLVM_) { VMWAIT(4); } else { VMWAIT(0); }                                         \
    RAWBAR();                                                                               \
    LGKM0();                                                                                \
    PH_MFMA(3);                                                                             \
    RAWBAR();                                                                               \
  } while (0)

  STG(Ab, 0, 0, sA, 0);
  STG(Ab, 0, 1, sA, 0);
  STG(Bb, 0, 0, sB, 0);
  STG(Bb, 0, 1, sB, 0);
  STG(Bb, 1, 0, sB, 1);
  STG(Bb, 1, 1, sB, 1);
  VMWAIT(4);
  RAWBAR();

  for (int t2 = 0; t2 < 7; ++t2) {
    const int t = t2 * 2;
    ITER(t, 0, 1, 1, 1);
    ITER(t + 1, 1, 1, 1, 1);
  }
  ITER(14, 0, 1, 0, 0);
  ITER(15, 1, 0, 0, 0);

#undef STG
#undef VMWAIT
#undef RAWBAR
#undef LGKM0
#undef PH_MFMA
#undef RD_AF
#undef ITER

#pragma unroll
  for (int ni = 0; ni < 4; ++ni) {
    int j = bn * 256 + wc * 64 + ni * 16 + l15;
    float bj = bias[j];
    int which = j >> 10, r = j & 1023, h = r >> 6, dd = r & 63;
#pragma unroll
    for (int mi = 0; mi < 8; ++mi) {
      int m0 = bm * 256 + wr * 128 + mi * 16 + g * 4;  // C/D: row=(l>>4)*4+reg, col=l&15
      float v[4];
#pragma unroll
      for (int rr = 0; rr < 4; ++rr) v[rr] = acc[mi][ni][rr] + bj;
      int b = m0 >> 11, nn = m0 & 2047;
      if (which < 2) {
#pragma unroll
        for (int rr = 0; rr < 4; ++rr)
          qk[(size_t)which * 4194304 + (((size_t)b * 16 + h) * 2048 + nn + rr) * 64 + dd] = (bf16)v[rr];
      } else {
        bf16x4 pw = {(bf16)v[0], (bf16)v[1], (bf16)v[2], (bf16)v[3]};
        *(bf16x4*)(vt + (((size_t)b * 16 + h) * 64 + dd) * 2048 + nn) = pw;
      }
    }
  }
}

// ---------------- 64x64 proj GEMM (r18): 1024 blocks = 4 blocks/CU = 16 waves/CU ----------------
// r16 proj was 2 blocks/CU (8 waves); proj is latency-bound at 8.6 GF so occupancy is the lever.
// Per-wave 64x16 output (acc[4] f32x4 = 16 VGPR). Per-element K-chain (kt 0..15, ks 0..1,
// MFMA16(af[mi], bfr, .)) identical to r16 -> bit-exact. XCD-chunked: 1024 = 8 x 128.
__global__ __launch_bounds__(256, 4) void k_gemm_proj(const bf16* __restrict__ A,
                                                      const bf16* __restrict__ BT,
                                                      const float* __restrict__ bias,
                                                      float* __restrict__ outf) {
  __shared__ __align__(16) unsigned char sA[8192];  // [64][64] bf16, swizzled 128B rows
  __shared__ __align__(16) unsigned char sB[8192];  // [64][64]
  const int tid = threadIdx.x;
  const int l = tid & 63, w = tid >> 6, g = l >> 4, l15 = l & 15;
  const int wg = (blockIdx.x & 7) * 128 + (blockIdx.x >> 3);
  const int bn = wg & 15, bm = wg >> 4;
  const unsigned char* Ab = (const unsigned char*)A + (size_t)bm * 64 * 2048;
  const unsigned char* Bb = (const unsigned char*)BT + (size_t)bn * 64 * 2048;
  f32x4 acc[4];
#pragma unroll
  for (int mi = 0; mi < 4; ++mi) acc[mi] = (f32x4){0.f, 0.f, 0.f, 0.f};

  const int co0 = tid * 16, co1 = tid * 16 + 4096;
  const int r0 = co0 >> 7, r1 = co1 >> 7;
  const int s0 = (co0 & 127) ^ ((r0 & 7) << 4), s1 = (co1 & 127) ^ ((r1 & 7) << 4);

  for (int kt = 0; kt < 16; ++kt) {
    const size_t k0b = (size_t)kt * 128;
    glds16(Ab + (size_t)r0 * 2048 + k0b + s0, sA + co0);
    glds16(Ab + (size_t)r1 * 2048 + k0b + s1, sA + co1);
    glds16(Bb + (size_t)r0 * 2048 + k0b + s0, sB + co0);
    glds16(Bb + (size_t)r1 * 2048 + k0b + s1, sB + co1);
    __syncthreads();
#pragma unroll
    for (int ks = 0; ks < 2; ++ks) {
      bf16x8 af[4], bfr;
#pragma unroll
      for (int mi = 0; mi < 4; ++mi) af[mi] = ldsfrag(sA, mi * 16 + l15, ks * 64 + g * 16);
      bfr = ldsfrag(sB, w * 16 + l15, ks * 64 + g * 16);
      __builtin_amdgcn_s_setprio(1);
#pragma unroll
      for (int mi = 0; mi < 4; ++mi) acc[mi] = MFMA16(af[mi], bfr, acc[mi]);
      __builtin_amdgcn_s_setprio(0);
    }
    __syncthreads();
  }
  {
    int j = bn * 64 + w * 16 + l15;
    float bj = bias[j];
#pragma unroll
    for (int mi = 0; mi < 4; ++mi) {
      int m0 = bm * 64 + mi * 16 + g * 4;
#pragma unroll
      for (int rr = 0; rr < 4; ++rr) outf[(size_t)(m0 + rr) * 1024 + j] = acc[mi][rr] + bj;
    }
  }
}

// ---------------- flash attention (r9/r14 structure, frozen; canary 9.766e-4) ----------------
__global__ __launch_bounds__(512, 1) void k_attn(const bf16* __restrict__ Qg, const bf16* __restrict__ Kg,
                                                 const bf16* __restrict__ VTg, bf16* __restrict__ Og) {
  __shared__ __align__(16) unsigned char smem[67584];
  const int tid = threadIdx.x;
  const int l = tid & 63, w = tid >> 6;
  const int q = l & 31, hi = l >> 5;
  const int g = w >> 2, wl = w & 3;
  const int stid = tid & 255;

  const int bid = blockIdx.x;                  // 256 blocks
  const int wg = (bid & 7) * 32 + (bid >> 3);  // XCD-chunked: 4 consecutive bh per XCD
  const int bh = wg >> 3;
  const int q0w = (wg & 7) * 256 + wl * 64;    // this wave's 64 q-rows

  bf16x8 qf[2][4];
#pragma unroll
  for (int qt = 0; qt < 2; ++qt)
#pragma unroll
    for (int ks = 0; ks < 4; ++ks)
      qf[qt][ks] = *(const bf16x8*)(Qg + ((size_t)bh * 2048 + q0w + qt * 32 + q) * 64 + ks * 16 + hi * 8);

  f32x16 oacc[2][2];
#pragma unroll
  for (int qt = 0; qt < 2; ++qt) { oacc[qt][0] = zero16(); oacc[qt][1] = zero16(); }
  float lrun4[2][4] = {{0.f, 0.f, 0.f, 0.f}, {0.f, 0.f, 0.f, 0.f}};
  bf16x8 pb[2][4];

  const unsigned char* Kb = (const unsigned char*)Kg + (size_t)bh * 262144 + (size_t)g * 131072;
  const unsigned char* Vb = (const unsigned char*)VTg + (size_t)bh * 262144 + (size_t)g * 2048;
  unsigned char* sKg = smem + g * 16384;
  unsigned char* sVg = smem + 32768 + g * 16384;

  const int co0 = stid * 16, co1 = (256 + stid) * 16;
  const int row0 = co0 >> 7, row1 = co1 >> 7;
  const int sw0 = (co0 & 127) ^ ((row0 & 7) << 4), sw1 = (co1 & 127) ^ ((row1 & 7) << 4);

#define STAGE_K(kb_, buf_)                                                        \
  do {                                                                            \
    const unsigned char* Ksrc = Kb + (size_t)(kb_) * 8192;                        \
    glds16(Ksrc + (co0 & ~127) + sw0, sKg + (buf_) * 8192 + co0);                 \
    glds16(Ksrc + (co1 & ~127) + sw1, sKg + (buf_) * 8192 + co1);                 \
  } while (0)
#define STAGE_V(kb_, buf_)                                                        \
  do {                                                                            \
    glds16(Vb + (size_t)row0 * 4096 + (size_t)(kb_) * 128 + sw0, sVg + (buf_) * 8192 + co0); \
    glds16(Vb + (size_t)row1 * 4096 + (size_t)(kb_) * 128 + sw1, sVg + (buf_) * 8192 + co1); \
  } while (0)

#define QK_EXP_PACK(kbase_)                                                       \
  do {                                                                            \
    _Pragma("unroll") for (int kt = 0; kt < 2; ++kt) {                            \
      bf16x8 kf[4];                                                               \
      _Pragma("unroll") for (int ks = 0; ks < 4; ++ks)                            \
        kf[ks] = ldsfrag((kbase_), kt * 32 + q, ks * 32 + hi * 16);               \
      _Pragma("unroll") for (int qt = 0; qt < 2; ++qt) {                          \
        f32x16 sacc = zero16();                                                   \
        __builtin_amdgcn_s_setprio(1);                                            \
        _Pragma("unroll") for (int ks = 0; ks < 4; ++ks)                          \
          sacc = MFMA32(kf[ks], qf[qt][ks], sacc);                                \
        __builtin_amdgcn_s_setprio(0);                                            \
        float pe[16];                                                             \
        _Pragma("unroll") for (int r = 0; r < 16; ++r) pe[r] = fexp2(sacc[r]);    \
        _Pragma("unroll") for (int m = 0; m < 4; ++m)                             \
          _Pragma("unroll") for (int j = 0; j < 4; ++j) lrun4[qt][j] += pe[4 * m + j]; \
        uint32_t c[4][2];                                                         \
        _Pragma("unroll") for (int m = 0; m < 4; ++m) {                           \
          c[m][0] = pkbf16(pe[4 * m], pe[4 * m + 1]);                             \
          c[m][1] = pkbf16(pe[4 * m + 2], pe[4 * m + 3]);                         \
        }                                                                         \
        _Pragma("unroll") for (int s = 0; s < 2; ++s) {                           \
          uint32_t x0 = c[2 * s][0], y0 = c[2 * s + 1][0];                        \
          uint32_t x1 = c[2 * s][1], y1 = c[2 * s + 1][1];                        \
          asm("v_permlane32_swap_b32 %0, %1" : "+v"(x0), "+v"(y0));               \
          asm("v_permlane32_swap_b32 %0, %1" : "+v"(x1), "+v"(y1));               \
          union { uint32_t u[4]; bf16x8 v; } bfr;                                 \
          bfr.u[0] = x0; bfr.u[1] = x1; bfr.u[2] = y0; bfr.u[3] = y1;             \
          pb[qt][kt * 2 + s] = bfr.v;                                             \
        }                                                                         \
      }                                                                           \
    }                                                                             \
  } while (0)

#define PV_TILE(vbase_)                                                           \
  do {                                                                            \
    __builtin_amdgcn_s_setprio(1);                                                \
    _Pragma("unroll") for (int ks = 0; ks < 4; ++ks)                              \
      _Pragma("unroll") for (int dt = 0; dt < 2; ++dt) {                          \
        bf16x8 vf = ldsfrag((vbase_), dt * 32 + q, ks * 32 + hi * 16);            \
        _Pragma("unroll") for (int qtp = 0; qtp < 2; ++qtp)                       \
          oacc[qtp][dt] = MFMA32(vf, pb[qtp][ks], oacc[qtp][dt]);                 \
      }                                                                           \
    __builtin_amdgcn_s_setprio(0);                                                \
  } while (0)

  STAGE_K(0, 0);
  STAGE_V(0, 0);
  __syncthreads();
  STAGE_K(1, 1);
  QK_EXP_PACK(sKg);
  __syncthreads();
  int cur = 0;

  for (int kb = 0; kb < 15; ++kb) {
    const int nxt = cur ^ 1;
    if (kb < 14) STAGE_K(kb + 2, cur);
    STAGE_V(kb + 1, nxt);
    PV_TILE(sVg + cur * 8192);
    QK_EXP_PACK(sKg + nxt * 8192);
    __syncthreads();
    cur = nxt;
  }
  PV_TILE(sVg + cur * 8192);

#undef STAGE_K
#undef STAGE_V
#undef QK_EXP_PACK
#undef PV_TILE

  float lrun[2];
#pragma unroll
  for (int qt = 0; qt < 2; ++qt)
    lrun[qt] = (lrun4[qt][0] + lrun4[qt][1]) + (lrun4[qt][2] + lrun4[qt][3]);

  float* mbuf = (float*)smem;
  float* lb = (float*)(smem + 65536);
  if (g == 1) {
#pragma unroll
    for (int qt = 0; qt < 2; ++qt) {
#pragma unroll
      for (int dt = 0; dt < 2; ++dt)
#pragma unroll
        for (int r = 0; r < 16; ++r)
          mbuf[((wl * 64 + qt * 32 + dt * 16 + r) << 6) + l] = oacc[qt][dt][r];
      lb[(wl * 2 + qt) * 64 + l] = lrun[qt];
    }
  }
  __syncthreads();
  if (g == 0) {
#pragma unroll
    for (int qt = 0; qt < 2; ++qt)
#pragma unroll
      for (int dt = 0; dt < 2; ++dt)
#pragma unroll
        for (int r = 0; r < 16; ++r)
          oacc[qt][dt][r] += mbuf[((wl * 64 + qt * 32 + dt * 16 + r) << 6) + l];
  }
  __syncthreads();
  if (g == 0) {
    const int b = bh >> 4, h = bh & 15;
    unsigned char* sO = smem + 32768 + wl * 4096;
#pragma unroll
    for (int qt = 0; qt < 2; ++qt) {
      float lr = lrun[qt] + lb[(wl * 2 + qt) * 64 + l];
      float ps = lr + __shfl_xor(lr, 32);
      float linv = 1.0f / ps;
#pragma unroll
      for (int dt = 0; dt < 2; ++dt)
#pragma unroll
        for (int m = 0; m < 4; ++m) {
          uint32_t b0 = pkbf16(oacc[qt][dt][4 * m] * linv, oacc[qt][dt][4 * m + 1] * linv);
          uint32_t b1 = pkbf16(oacc[qt][dt][4 * m + 2] * linv, oacc[qt][dt][4 * m + 3] * linv);
          int byteo = (dt * 64 + m * 16 + hi * 8) ^ ((q & 7) << 4);
          uint32_t* dst = (uint32_t*)(sO + q * 128 + byteo);
          dst[0] = b0; dst[1] = b1;
        }
      const int q0 = q0w + qt * 32;
#pragma unroll
      for (int rd = 0; rd < 4; ++rd) {
        int byteo = hi * 64 + rd * 16;
        bf16x8 v = *(const bf16x8*)(sO + q * 128 + (byteo ^ ((q & 7) << 4)));
        *(bf16x8*)(Og + ((size_t)b * 2048 + q0 + q) * 1024 + h * 64 + byteo / 2) = v;
      }
    }
  }
}

extern "C" void kernel_launch(void* const* d_in, const int* in_sizes, int n_in,
                              void* d_out, int out_size, void* d_ws, size_t ws_size,
                              hipStream_t stream) {
  const float* x = (const float*)d_in[0];
  const float* Wqkv = (const float*)d_in[1];
  const float* bqkv = (const float*)d_in[2];
  const float* Wproj = (const float*)d_in[3];
  const float* bproj = (const float*)d_in[4];
  float* out = (float*)d_out;
  char* ws = (char*)d_ws;

  bf16* XB = (bf16*)(ws + 0);            // 8 MB x_bf16 [4096][1024]; reused as attn-out
  bf16* WQT = (bf16*)(ws + 8388608);     // 6 MB WqkvT (permuted, Q pre-scaled) [3072][1024]
  float* BQP = (float*)(ws + 14680064);  // 16 KB permuted bias (Q part pre-scaled)
  bf16* WPT = (bf16*)(ws + 14696448);    // 2 MB WprojT [1024][1024]
  bf16* Q = (bf16*)(ws + 16793600);      // 8 MB [2][16][2048][64]
  bf16* K = (bf16*)(ws + 25182208);      // 8 MB (contiguous after Q: qk base + 4194304 elems)
  bf16* VT = (bf16*)(ws + 33570816);     // 8 MB [2][16][64][2048] (written directly by gemm)
  bf16* AO = XB;
  (void)K;
  (void)ws_size;

  k_prep_all<<<2316, 256, 0, stream>>>(x, Wqkv, bqkv, Wproj, XB, WQT, WPT, BQP);
  k_gemm_qkv8<<<192, 512, 0, stream>>>(XB, WQT, BQP, Q, VT);
  k_attn<<<256, 512, 0, stream>>>(Q, Q + 4194304, VT, AO);
  k_gemm_proj<<<1024, 256, 0, stream>>>(AO, WPT, bproj, out);
}